// Round 1
// baseline (359.472 us; speedup 1.0000x reference)
//
#include <hip/hip_runtime.h>
#include <hip/hip_bf16.h>
#include <stdint.h>

// Problem constants (from reference): B=1, S=2048, H=1024, I=512, E=16, K=4
#define HH 1024
#define II 512
#define EE 16
#define TT 2048
#define KTOP 4
#define PP (TT * KTOP)      // 8192 routed pairs
#define MAXROWS 12288       // padded row capacity (<= 8192 + 16*127 = 10224 used)

typedef unsigned short u16;
typedef __attribute__((ext_vector_type(8))) short short8;       // bf16 MFMA A/B frag (4 VGPR)
typedef __attribute__((ext_vector_type(4))) float f32x4;        // MFMA C/D frag
typedef __attribute__((ext_vector_type(4))) unsigned short u16x4;
typedef __attribute__((ext_vector_type(8))) unsigned short u16x8;
typedef __attribute__((ext_vector_type(4))) unsigned int u32x4;

__device__ __forceinline__ u16 f2bf(float f) {  // fp32 -> bf16 RNE
  union { float f; unsigned u; } v; v.f = f;
  unsigned r = v.u + 0x7fffu + ((v.u >> 16) & 1u);
  return (u16)(r >> 16);
}

// ---------------- prep: x fp32 -> bf16 ----------------
__global__ void cvt_x_kernel(const float* __restrict__ x, u16* __restrict__ xb) {
  const int i = (blockIdx.x * 256 + threadIdx.x) * 4;
  f32x4 v = *(const f32x4*)(x + i);
  u16x4 o = { f2bf(v[0]), f2bf(v[1]), f2bf(v[2]), f2bf(v[3]) };
  *(u16x4*)(xb + i) = o;
}

// ---------------- prep: weight [R][C] fp32 -> [C][R] bf16 (per expert z) ----------------
__global__ void transpose_cvt(const float* __restrict__ src, u16* __restrict__ dst,
                              int R, int C) {
  __shared__ u16 tile[64][72];   // +8 pad breaks write/read bank alignment
  const size_t mat = (size_t)blockIdx.z * R * C;
  const int r0 = blockIdx.y * 64, c0 = blockIdx.x * 64;
  const int tid = threadIdx.x;          // 256 threads
  const int row = tid >> 2, cg = (tid & 3) * 16;
  const float* sp = src + mat + (size_t)(r0 + row) * C + c0 + cg;
#pragma unroll
  for (int j = 0; j < 16; j += 4) {
    f32x4 v = *(const f32x4*)(sp + j);
    tile[row][cg + j + 0] = f2bf(v[0]);
    tile[row][cg + j + 1] = f2bf(v[1]);
    tile[row][cg + j + 2] = f2bf(v[2]);
    tile[row][cg + j + 3] = f2bf(v[3]);
  }
  __syncthreads();
  u16* dp = dst + mat + (size_t)(c0 + row) * R + r0 + cg;
  u16x8 o0, o1;
#pragma unroll
  for (int j = 0; j < 8; j++) o0[j] = tile[cg + j][row];
#pragma unroll
  for (int j = 0; j < 8; j++) o1[j] = tile[cg + 8 + j][row];
  *(u16x8*)(dp) = o0;
  *(u16x8*)(dp + 8) = o1;
}

// ---------------- routing: deterministic per-expert compaction ----------------
// One block, 16 waves; wave w owns expert w. Last-duplicate-wins dedup matches the
// reference's scatter-set semantics. Each expert's list padded to a multiple of 128
// with (token 0, weight 0) so GEMM tiles never need bounds checks.
__global__ void route_kernel(const int* __restrict__ tidx, const float* __restrict__ tw,
                             int* __restrict__ perm, float* __restrict__ wt,
                             int* __restrict__ tile_e, int* __restrict__ tile_r,
                             int* __restrict__ ntiles) {
  __shared__ int cnt[EE];
  __shared__ int offs[EE];
  const int lane = threadIdx.x & 63;
  const int wid = threadIdx.x >> 6;

  int c = 0;
  for (int base = 0; base < PP; base += 64) {
    int p = base + lane;
    int t = p >> 2, k = p & 3;
    int e = tidx[p];
    bool valid = true;
    for (int k2 = k + 1; k2 < 4; k2++) valid = valid && (tidx[t * 4 + k2] != e);
    unsigned long long m = __ballot(valid && (e == wid));
    c += __popcll(m);
  }
  if (lane == 0) cnt[wid] = c;
  __syncthreads();
  if (threadIdx.x == 0) {
    int off = 0, nt = 0;
    for (int e = 0; e < EE; e++) {
      offs[e] = off;
      int cp = (cnt[e] + 127) & ~127;
      for (int m0 = 0; m0 < cp; m0 += 128) { tile_e[nt] = e; tile_r[nt] = off + m0; nt++; }
      off += cp;
    }
    *ntiles = nt;
  }
  __syncthreads();
  int off = offs[wid];
  for (int base = 0; base < PP; base += 64) {
    int p = base + lane;
    int t = p >> 2, k = p & 3;
    int e = tidx[p];
    bool valid = true;
    for (int k2 = k + 1; k2 < 4; k2++) valid = valid && (tidx[t * 4 + k2] != e);
    bool mm = valid && (e == wid);
    unsigned long long mask = __ballot(mm);
    if (mm) {
      int pre = __popcll(mask & ((1ull << lane) - 1ull));
      perm[off + pre] = t;
      wt[off + pre] = tw[p];
    }
    off += __popcll(mask);
  }
  int cp = (cnt[wid] + 127) & ~127;
  for (int i = offs[wid] + cnt[wid] + lane; i < offs[wid] + cp; i += 64) {
    perm[i] = 0;          // pad: token 0 with weight 0 contributes exactly nothing
    wt[i] = 0.f;
  }
}

// ---------------- GEMM1: ACT[r][i] = silu(x@Wg) * (x@Wu) * gate_weight, bf16 ----------------
// Tile 128(M) x 64(N), BK=32, 4 waves as 2x2; each wave 64x32 = 4x2 MFMA frags, dual acc.
__global__ __launch_bounds__(256) void gemm1_kernel(
    const u16* __restrict__ xb, const u16* __restrict__ WgT, const u16* __restrict__ WuT,
    const int* __restrict__ perm, const float* __restrict__ wt,
    const int* __restrict__ tile_e, const int* __restrict__ tile_r,
    const int* __restrict__ ntiles, u16* __restrict__ ACT) {
  const int tileid = blockIdx.y;
  if (tileid >= *ntiles) return;
  const int e = tile_e[tileid];
  const int row0 = tile_r[tileid];
  const int n0 = blockIdx.x * 64;

  __shared__ __align__(16) u16 As[128 * 32];
  __shared__ __align__(16) u16 Gs[64 * 32];
  __shared__ __align__(16) u16 Us[64 * 32];

  const int tid = threadIdx.x;
  const int lane = tid & 63;
  const int wid = tid >> 6;
  const int wm = wid >> 1, wn = wid & 1;
  const int fr = lane & 15, fq = lane >> 4;

  const int srow = tid >> 2;             // 0..63
  const int scol = (tid & 3) * 8;        // 0/8/16/24

  const int tok0 = perm[row0 + srow];
  const int tok1 = perm[row0 + 64 + srow];
  const size_t aoff0 = (size_t)tok0 * HH + scol;
  const size_t aoff1 = (size_t)tok1 * HH + scol;
  const size_t boff = ((size_t)e * II + n0 + srow) * HH + scol;

  f32x4 accg[4][2], accu[4][2];
  const f32x4 vz = {0.f, 0.f, 0.f, 0.f};
#pragma unroll
  for (int m = 0; m < 4; m++)
#pragma unroll
    for (int n = 0; n < 2; n++) { accg[m][n] = vz; accu[m][n] = vz; }

  for (int k0 = 0; k0 < HH; k0 += 32) {
    u32x4 a0 = *(const u32x4*)(xb + aoff0 + k0);
    u32x4 a1 = *(const u32x4*)(xb + aoff1 + k0);
    u32x4 g0 = *(const u32x4*)(WgT + boff + k0);
    u32x4 u0 = *(const u32x4*)(WuT + boff + k0);
    __syncthreads();
    *(u32x4*)(&As[srow * 32 + scol]) = a0;
    *(u32x4*)(&As[(64 + srow) * 32 + scol]) = a1;
    *(u32x4*)(&Gs[srow * 32 + scol]) = g0;
    *(u32x4*)(&Us[srow * 32 + scol]) = u0;
    __syncthreads();

    short8 af[4], bg[2], bu[2];
#pragma unroll
    for (int m = 0; m < 4; m++)
      af[m] = *(const short8*)(&As[(wm * 64 + m * 16 + fr) * 32 + fq * 8]);
#pragma unroll
    for (int n = 0; n < 2; n++) {
      bg[n] = *(const short8*)(&Gs[(wn * 32 + n * 16 + fr) * 32 + fq * 8]);
      bu[n] = *(const short8*)(&Us[(wn * 32 + n * 16 + fr) * 32 + fq * 8]);
    }
#pragma unroll
    for (int m = 0; m < 4; m++)
#pragma unroll
      for (int n = 0; n < 2; n++) {
        accg[m][n] = __builtin_amdgcn_mfma_f32_16x16x32_bf16(af[m], bg[n], accg[m][n], 0, 0, 0);
        accu[m][n] = __builtin_amdgcn_mfma_f32_16x16x32_bf16(af[m], bu[n], accu[m][n], 0, 0, 0);
      }
  }

  // C/D layout: col = lane&15, row = (lane>>4)*4 + j  [verified mapping]
#pragma unroll
  for (int m = 0; m < 4; m++) {
    const int rbase = wm * 64 + m * 16 + fq * 4;
#pragma unroll
    for (int j = 0; j < 4; j++) {
      const int rloc = rbase + j;
      const float w = wt[row0 + rloc];
#pragma unroll
      for (int n = 0; n < 2; n++) {
        const float g = accg[m][n][j];
        const float u = accu[m][n][j];
        const float s = g / (1.f + __expf(-g));   // silu
        ACT[(size_t)(row0 + rloc) * II + n0 + (wn * 32 + n * 16 + fr)] = f2bf(s * u * w);
      }
    }
  }
}

// ---------------- GEMM2: out[token][h] += ACT @ Wd  (fp32 atomics) ----------------
// Tile 128(M) x 128(N), BK=32, 4 waves as 2x2; each wave 64x64 = 4x4 frags.
__global__ __launch_bounds__(256) void gemm2_kernel(
    const u16* __restrict__ ACT, const u16* __restrict__ WdT,
    const int* __restrict__ perm,
    const int* __restrict__ tile_e, const int* __restrict__ tile_r,
    const int* __restrict__ ntiles, float* __restrict__ out) {
  const int tileid = blockIdx.y;
  if (tileid >= *ntiles) return;
  const int e = tile_e[tileid];
  const int row0 = tile_r[tileid];
  const int n0 = blockIdx.x * 128;

  __shared__ __align__(16) u16 As[128 * 32];
  __shared__ __align__(16) u16 Bs[128 * 32];

  const int tid = threadIdx.x;
  const int lane = tid & 63;
  const int wid = tid >> 6;
  const int wm = wid >> 1, wn = wid & 1;
  const int fr = lane & 15, fq = lane >> 4;

  const int srow = tid >> 2;
  const int scol = (tid & 3) * 8;

  const size_t aoff0 = (size_t)(row0 + srow) * II + scol;
  const size_t aoff1 = (size_t)(row0 + 64 + srow) * II + scol;
  const size_t boff0 = ((size_t)e * HH + n0 + srow) * II + scol;
  const size_t boff1 = ((size_t)e * HH + n0 + 64 + srow) * II + scol;

  f32x4 acc[4][4];
  const f32x4 vz = {0.f, 0.f, 0.f, 0.f};
#pragma unroll
  for (int m = 0; m < 4; m++)
#pragma unroll
    for (int n = 0; n < 4; n++) acc[m][n] = vz;

  for (int k0 = 0; k0 < II; k0 += 32) {
    u32x4 a0 = *(const u32x4*)(ACT + aoff0 + k0);
    u32x4 a1 = *(const u32x4*)(ACT + aoff1 + k0);
    u32x4 b0 = *(const u32x4*)(WdT + boff0 + k0);
    u32x4 b1 = *(const u32x4*)(WdT + boff1 + k0);
    __syncthreads();
    *(u32x4*)(&As[srow * 32 + scol]) = a0;
    *(u32x4*)(&As[(64 + srow) * 32 + scol]) = a1;
    *(u32x4*)(&Bs[srow * 32 + scol]) = b0;
    *(u32x4*)(&Bs[(64 + srow) * 32 + scol]) = b1;
    __syncthreads();

    short8 af[4], bf[4];
#pragma unroll
    for (int m = 0; m < 4; m++)
      af[m] = *(const short8*)(&As[(wm * 64 + m * 16 + fr) * 32 + fq * 8]);
#pragma unroll
    for (int n = 0; n < 4; n++)
      bf[n] = *(const short8*)(&Bs[(wn * 64 + n * 16 + fr) * 32 + fq * 8]);
#pragma unroll
    for (int m = 0; m < 4; m++)
#pragma unroll
      for (int n = 0; n < 4; n++)
        acc[m][n] = __builtin_amdgcn_mfma_f32_16x16x32_bf16(af[m], bf[n], acc[m][n], 0, 0, 0);
  }

#pragma unroll
  for (int m = 0; m < 4; m++) {
    const int rbase = wm * 64 + m * 16 + fq * 4;
#pragma unroll
    for (int j = 0; j < 4; j++) {
      const int tok = perm[row0 + rbase + j];
      float* op = out + (size_t)tok * HH + n0 + wn * 64 + fr;
#pragma unroll
      for (int n = 0; n < 4; n++)
        atomicAdd(op + n * 16, acc[m][n][j]);
    }
  }
}

// ---------------- launch ----------------
extern "C" void kernel_launch(void* const* d_in, const int* in_sizes, int n_in,
                              void* d_out, int out_size, void* d_ws, size_t ws_size,
                              hipStream_t stream) {
  const float* x = (const float*)d_in[0];
  const int* tidx = (const int*)d_in[1];
  const float* tw = (const float*)d_in[2];
  const float* wg = (const float*)d_in[3];
  const float* wu = (const float*)d_in[4];
  const float* wd = (const float*)d_in[5];
  float* out = (float*)d_out;

  // ws layout (bytes); total ~64.1 MB
  char* ws = (char*)d_ws;
  int* ntiles = (int*)(ws + 0);
  int* tile_e = (int*)(ws + 1024);
  int* tile_r = (int*)(ws + 2048);
  int* perm = (int*)(ws + 4096);                 // 12288 ints
  float* wt = (float*)(ws + 53248);              // 12288 floats
  u16* xb = (u16*)(ws + 131072);                 // [2048][1024] bf16, 4 MB
  u16* WgT = (u16*)(ws + 4325376);               // [E][I][H] bf16, 16 MB
  u16* WuT = (u16*)(ws + 21102592);              // [E][I][H] bf16, 16 MB
  u16* WdT = (u16*)(ws + 37879808);              // [E][H][I] bf16, 16 MB
  u16* ACT = (u16*)(ws + 54657024);              // [MAXROWS][I] bf16, 12 MB

  hipMemsetAsync(out, 0, (size_t)TT * HH * sizeof(float), stream);
  cvt_x_kernel<<<TT * HH / 1024, 256, 0, stream>>>(x, xb);
  transpose_cvt<<<dim3(II / 64, HH / 64, EE), 256, 0, stream>>>(wg, WgT, HH, II);
  transpose_cvt<<<dim3(II / 64, HH / 64, EE), 256, 0, stream>>>(wu, WuT, HH, II);
  transpose_cvt<<<dim3(HH / 64, II / 64, EE), 256, 0, stream>>>(wd, WdT, II, HH);
  route_kernel<<<1, 1024, 0, stream>>>(tidx, tw, perm, wt, tile_e, tile_r, ntiles);
  gemm1_kernel<<<dim3(II / 64, 80), 256, 0, stream>>>(xb, WgT, WuT, perm, wt,
                                                      tile_e, tile_r, ntiles, ACT);
  gemm2_kernel<<<dim3(HH / 128, 80), 256, 0, stream>>>(ACT, WdT, perm,
                                                       tile_e, tile_r, ntiles, out);
}

// Round 2
// 197.137 us; speedup vs baseline: 1.8235x; 1.8235x over previous
//
#include <hip/hip_runtime.h>
#include <hip/hip_bf16.h>
#include <stdint.h>

// Problem constants (from reference): B=1, S=2048, H=1024, I=512, E=16, K=4
#define HH 1024
#define II 512
#define EE 16
#define TT 2048
#define KTOP 4
#define PP (TT * KTOP)      // 8192 routed pairs
#define MAXROWS 12288       // padded row capacity (<= 8192 + 16*127 = 10224 used)

typedef unsigned short u16;
typedef __attribute__((ext_vector_type(8))) short short8;       // bf16 MFMA A/B frag (4 VGPR)
typedef __attribute__((ext_vector_type(4))) float f32x4;        // MFMA C/D frag
typedef __attribute__((ext_vector_type(4))) unsigned short u16x4;
typedef __attribute__((ext_vector_type(8))) unsigned short u16x8;
typedef __attribute__((ext_vector_type(4))) unsigned int u32x4;

__device__ __forceinline__ u16 f2bf(float f) {  // fp32 -> bf16 RNE
  union { float f; unsigned u; } v; v.f = f;
  unsigned r = v.u + 0x7fffu + ((v.u >> 16) & 1u);
  return (u16)(r >> 16);
}

// ---------------- prep: x fp32 -> bf16 ----------------
__global__ void cvt_x_kernel(const float* __restrict__ x, u16* __restrict__ xb) {
  const int i = (blockIdx.x * 256 + threadIdx.x) * 4;
  f32x4 v = *(const f32x4*)(x + i);
  u16x4 o = { f2bf(v[0]), f2bf(v[1]), f2bf(v[2]), f2bf(v[3]) };
  *(u16x4*)(xb + i) = o;
}

// ---------------- prep: weight [R][C] fp32 -> [C][R] bf16 (per expert z) ----------------
__global__ void transpose_cvt(const float* __restrict__ src, u16* __restrict__ dst,
                              int R, int C) {
  __shared__ u16 tile[64][72];   // +8 pad breaks write/read bank alignment
  const size_t mat = (size_t)blockIdx.z * R * C;
  const int r0 = blockIdx.y * 64, c0 = blockIdx.x * 64;
  const int tid = threadIdx.x;          // 256 threads
  const int row = tid >> 2, cg = (tid & 3) * 16;
  const float* sp = src + mat + (size_t)(r0 + row) * C + c0 + cg;
#pragma unroll
  for (int j = 0; j < 16; j += 4) {
    f32x4 v = *(const f32x4*)(sp + j);
    tile[row][cg + j + 0] = f2bf(v[0]);
    tile[row][cg + j + 1] = f2bf(v[1]);
    tile[row][cg + j + 2] = f2bf(v[2]);
    tile[row][cg + j + 3] = f2bf(v[3]);
  }
  __syncthreads();
  u16* dp = dst + mat + (size_t)(c0 + row) * R + r0 + cg;
  u16x8 o0, o1;
#pragma unroll
  for (int j = 0; j < 8; j++) o0[j] = tile[cg + j][row];
#pragma unroll
  for (int j = 0; j < 8; j++) o1[j] = tile[cg + 8 + j][row];
  *(u16x8*)(dp) = o0;
  *(u16x8*)(dp + 8) = o1;
}

// ---------------- routing: hierarchical deterministic compaction ----------------
// 1 block, 1024 threads (16 waves). Rank of pair p within its expert's list is
// computed in p-order: wave w ranks segment [512w,512w+512) via 16 unrolled
// ballots per 64-chunk; block-level bases come from a tiny LDS scan.
// Last-duplicate-wins dedup matches the reference's scatter-set semantics.
// Expert lists padded to x128 with (token 0, weight 0) -> pads contribute 0.
__global__ __launch_bounds__(1024) void route_kernel(
    const int* __restrict__ tidx, const float* __restrict__ tw,
    int* __restrict__ perm, float* __restrict__ wt,
    int* __restrict__ tile_e, int* __restrict__ tile_r,
    int* __restrict__ ntiles) {
  __shared__ int s_e[PP];          // bits0-3: e, bit4: valid, bits16+: in-segment rank
  __shared__ int whist[16][16];    // [wave][expert] segment counts
  __shared__ int wbase[16][16];    // [wave][expert] global base position
  __shared__ int pad_lo[EE], pad_hi[EE];

  const int tid = threadIdx.x;
  const int lane = tid & 63;
  const int wv = tid >> 6;

  // Phase 1: load topk_idx (int4 per token), validity, pack to LDS
#pragma unroll
  for (int i = 0; i < 2; i++) {
    const int t = tid + i * 1024;
    const int4 v = ((const int4*)tidx)[t];
    const bool v0 = (v.x != v.y) && (v.x != v.z) && (v.x != v.w);
    const bool v1 = (v.y != v.z) && (v.y != v.w);
    const bool v2 = (v.z != v.w);
    s_e[t * 4 + 0] = v.x | (v0 ? 16 : 0);
    s_e[t * 4 + 1] = v.y | (v1 ? 16 : 0);
    s_e[t * 4 + 2] = v.z | (v2 ? 16 : 0);
    s_e[t * 4 + 3] = v.w | 16;
  }
  __syncthreads();

  // Phase 2: per-wave in-order ranking of its 512-pair segment
  int h0, h1, h2, h3, h4, h5, h6, h7, h8, h9, h10, h11, h12, h13, h14, h15;
  h0=h1=h2=h3=h4=h5=h6=h7=h8=h9=h10=h11=h12=h13=h14=h15=0;
  const unsigned long long ltm = (1ull << lane) - 1ull;
  for (int c = 0; c < 8; c++) {
    const int p = (wv << 9) + (c << 6) + lane;
    const int se = s_e[p];
    const int e = se & 15;
    const bool valid = (se & 16) != 0;
    int rank = 0;
#define RANK_STEP(J, HJ)                                            \
    {                                                               \
      unsigned long long m = __ballot(valid && (e == J));           \
      if (valid && (e == J)) rank = HJ + __popcll(m & ltm);         \
      HJ += __popcll(m);                                            \
    }
    RANK_STEP(0, h0)  RANK_STEP(1, h1)  RANK_STEP(2, h2)  RANK_STEP(3, h3)
    RANK_STEP(4, h4)  RANK_STEP(5, h5)  RANK_STEP(6, h6)  RANK_STEP(7, h7)
    RANK_STEP(8, h8)  RANK_STEP(9, h9)  RANK_STEP(10, h10) RANK_STEP(11, h11)
    RANK_STEP(12, h12) RANK_STEP(13, h13) RANK_STEP(14, h14) RANK_STEP(15, h15)
#undef RANK_STEP
    if (valid) s_e[p] = se | (rank << 16);
  }
  if (lane == 0) {
    whist[wv][0] = h0;   whist[wv][1] = h1;   whist[wv][2] = h2;   whist[wv][3] = h3;
    whist[wv][4] = h4;   whist[wv][5] = h5;   whist[wv][6] = h6;   whist[wv][7] = h7;
    whist[wv][8] = h8;   whist[wv][9] = h9;   whist[wv][10] = h10; whist[wv][11] = h11;
    whist[wv][12] = h12; whist[wv][13] = h13; whist[wv][14] = h14; whist[wv][15] = h15;
  }
  __syncthreads();

  // Phase 3: tiny scan -> per-(wave,expert) bases, tile table, pad ranges
  if (tid == 0) {
    int off = 0, nt = 0;
    for (int j = 0; j < EE; j++) {
      int tot = 0;
      for (int w = 0; w < 16; w++) { wbase[w][j] = off + tot; tot += whist[w][j]; }
      const int cap = (tot + 127) & ~127;
      pad_lo[j] = off + tot;
      pad_hi[j] = off + cap;
      for (int m0 = 0; m0 < cap; m0 += 128) { tile_e[nt] = j; tile_r[nt] = off + m0; nt++; }
      off += cap;
    }
    *ntiles = nt;
  }
  __syncthreads();

  // Phase 4: scatter perm/wt (coalesced tw reads), then pad fill
#pragma unroll
  for (int i = 0; i < 8; i++) {
    const int p = i * 1024 + tid;
    const int se = s_e[p];
    if (se & 16) {
      const int e = se & 15;
      const int r = se >> 16;
      const int pos = wbase[p >> 9][e] + r;
      perm[pos] = p >> 2;
      wt[pos] = tw[p];
    }
  }
  for (int j = 0; j < EE; j++) {
    const int lo = pad_lo[j], hi = pad_hi[j];
    for (int i = lo + tid; i < hi; i += 1024) {
      perm[i] = 0;          // pad: token 0 with weight 0 contributes exactly nothing
      wt[i] = 0.f;
    }
  }
}

// ---------------- GEMM1: ACT[r][i] = silu(x@Wg) * (x@Wu) * gate_weight, bf16 ----------------
// Tile 128(M) x 64(N), BK=32, 4 waves as 2x2; each wave 64x32 = 4x2 MFMA frags, dual acc.
__global__ __launch_bounds__(256) void gemm1_kernel(
    const u16* __restrict__ xb, const u16* __restrict__ WgT, const u16* __restrict__ WuT,
    const int* __restrict__ perm, const float* __restrict__ wt,
    const int* __restrict__ tile_e, const int* __restrict__ tile_r,
    const int* __restrict__ ntiles, u16* __restrict__ ACT) {
  const int tileid = blockIdx.y;
  if (tileid >= *ntiles) return;
  const int e = tile_e[tileid];
  const int row0 = tile_r[tileid];
  const int n0 = blockIdx.x * 64;

  __shared__ __align__(16) u16 As[128 * 32];
  __shared__ __align__(16) u16 Gs[64 * 32];
  __shared__ __align__(16) u16 Us[64 * 32];

  const int tid = threadIdx.x;
  const int lane = tid & 63;
  const int wid = tid >> 6;
  const int wm = wid >> 1, wn = wid & 1;
  const int fr = lane & 15, fq = lane >> 4;

  const int srow = tid >> 2;             // 0..63
  const int scol = (tid & 3) * 8;        // 0/8/16/24

  const int tok0 = perm[row0 + srow];
  const int tok1 = perm[row0 + 64 + srow];
  const size_t aoff0 = (size_t)tok0 * HH + scol;
  const size_t aoff1 = (size_t)tok1 * HH + scol;
  const size_t boff = ((size_t)e * II + n0 + srow) * HH + scol;

  f32x4 accg[4][2], accu[4][2];
  const f32x4 vz = {0.f, 0.f, 0.f, 0.f};
#pragma unroll
  for (int m = 0; m < 4; m++)
#pragma unroll
    for (int n = 0; n < 2; n++) { accg[m][n] = vz; accu[m][n] = vz; }

  for (int k0 = 0; k0 < HH; k0 += 32) {
    u32x4 a0 = *(const u32x4*)(xb + aoff0 + k0);
    u32x4 a1 = *(const u32x4*)(xb + aoff1 + k0);
    u32x4 g0 = *(const u32x4*)(WgT + boff + k0);
    u32x4 u0 = *(const u32x4*)(WuT + boff + k0);
    __syncthreads();
    *(u32x4*)(&As[srow * 32 + scol]) = a0;
    *(u32x4*)(&As[(64 + srow) * 32 + scol]) = a1;
    *(u32x4*)(&Gs[srow * 32 + scol]) = g0;
    *(u32x4*)(&Us[srow * 32 + scol]) = u0;
    __syncthreads();

    short8 af[4], bg[2], bu[2];
#pragma unroll
    for (int m = 0; m < 4; m++)
      af[m] = *(const short8*)(&As[(wm * 64 + m * 16 + fr) * 32 + fq * 8]);
#pragma unroll
    for (int n = 0; n < 2; n++) {
      bg[n] = *(const short8*)(&Gs[(wn * 32 + n * 16 + fr) * 32 + fq * 8]);
      bu[n] = *(const short8*)(&Us[(wn * 32 + n * 16 + fr) * 32 + fq * 8]);
    }
#pragma unroll
    for (int m = 0; m < 4; m++)
#pragma unroll
      for (int n = 0; n < 2; n++) {
        accg[m][n] = __builtin_amdgcn_mfma_f32_16x16x32_bf16(af[m], bg[n], accg[m][n], 0, 0, 0);
        accu[m][n] = __builtin_amdgcn_mfma_f32_16x16x32_bf16(af[m], bu[n], accu[m][n], 0, 0, 0);
      }
  }

  // C/D layout: col = lane&15, row = (lane>>4)*4 + j  [verified mapping]
#pragma unroll
  for (int m = 0; m < 4; m++) {
    const int rbase = wm * 64 + m * 16 + fq * 4;
#pragma unroll
    for (int j = 0; j < 4; j++) {
      const int rloc = rbase + j;
      const float w = wt[row0 + rloc];
#pragma unroll
      for (int n = 0; n < 2; n++) {
        const float g = accg[m][n][j];
        const float u = accu[m][n][j];
        const float s = g / (1.f + __expf(-g));   // silu
        ACT[(size_t)(row0 + rloc) * II + n0 + (wn * 32 + n * 16 + fr)] = f2bf(s * u * w);
      }
    }
  }
}

// ---------------- GEMM2: out[token][h] += ACT @ Wd  (fp32 atomics) ----------------
// Tile 128(M) x 128(N), BK=32, 4 waves as 2x2; each wave 64x64 = 4x4 frags.
__global__ __launch_bounds__(256) void gemm2_kernel(
    const u16* __restrict__ ACT, const u16* __restrict__ WdT,
    const int* __restrict__ perm,
    const int* __restrict__ tile_e, const int* __restrict__ tile_r,
    const int* __restrict__ ntiles, float* __restrict__ out) {
  const int tileid = blockIdx.y;
  if (tileid >= *ntiles) return;
  const int e = tile_e[tileid];
  const int row0 = tile_r[tileid];
  const int n0 = blockIdx.x * 128;

  __shared__ __align__(16) u16 As[128 * 32];
  __shared__ __align__(16) u16 Bs[128 * 32];

  const int tid = threadIdx.x;
  const int lane = tid & 63;
  const int wid = tid >> 6;
  const int wm = wid >> 1, wn = wid & 1;
  const int fr = lane & 15, fq = lane >> 4;

  const int srow = tid >> 2;
  const int scol = (tid & 3) * 8;

  const size_t aoff0 = (size_t)(row0 + srow) * II + scol;
  const size_t aoff1 = (size_t)(row0 + 64 + srow) * II + scol;
  const size_t boff0 = ((size_t)e * HH + n0 + srow) * II + scol;
  const size_t boff1 = ((size_t)e * HH + n0 + 64 + srow) * II + scol;

  f32x4 acc[4][4];
  const f32x4 vz = {0.f, 0.f, 0.f, 0.f};
#pragma unroll
  for (int m = 0; m < 4; m++)
#pragma unroll
    for (int n = 0; n < 4; n++) acc[m][n] = vz;

  for (int k0 = 0; k0 < II; k0 += 32) {
    u32x4 a0 = *(const u32x4*)(ACT + aoff0 + k0);
    u32x4 a1 = *(const u32x4*)(ACT + aoff1 + k0);
    u32x4 b0 = *(const u32x4*)(WdT + boff0 + k0);
    u32x4 b1 = *(const u32x4*)(WdT + boff1 + k0);
    __syncthreads();
    *(u32x4*)(&As[srow * 32 + scol]) = a0;
    *(u32x4*)(&As[(64 + srow) * 32 + scol]) = a1;
    *(u32x4*)(&Bs[srow * 32 + scol]) = b0;
    *(u32x4*)(&Bs[(64 + srow) * 32 + scol]) = b1;
    __syncthreads();

    short8 af[4], bf[4];
#pragma unroll
    for (int m = 0; m < 4; m++)
      af[m] = *(const short8*)(&As[(wm * 64 + m * 16 + fr) * 32 + fq * 8]);
#pragma unroll
    for (int n = 0; n < 4; n++)
      bf[n] = *(const short8*)(&Bs[(wn * 64 + n * 16 + fr) * 32 + fq * 8]);
#pragma unroll
    for (int m = 0; m < 4; m++)
#pragma unroll
      for (int n = 0; n < 4; n++)
        acc[m][n] = __builtin_amdgcn_mfma_f32_16x16x32_bf16(af[m], bf[n], acc[m][n], 0, 0, 0);
  }

#pragma unroll
  for (int m = 0; m < 4; m++) {
    const int rbase = wm * 64 + m * 16 + fq * 4;
#pragma unroll
    for (int j = 0; j < 4; j++) {
      const int tok = perm[row0 + rbase + j];
      float* op = out + (size_t)tok * HH + n0 + wn * 64 + fr;
#pragma unroll
      for (int n = 0; n < 4; n++)
        atomicAdd(op + n * 16, acc[m][n][j]);
    }
  }
}

// ---------------- launch ----------------
extern "C" void kernel_launch(void* const* d_in, const int* in_sizes, int n_in,
                              void* d_out, int out_size, void* d_ws, size_t ws_size,
                              hipStream_t stream) {
  const float* x = (const float*)d_in[0];
  const int* tidx = (const int*)d_in[1];
  const float* tw = (const float*)d_in[2];
  const float* wg = (const float*)d_in[3];
  const float* wu = (const float*)d_in[4];
  const float* wd = (const float*)d_in[5];
  float* out = (float*)d_out;

  // ws layout (bytes); total ~64.1 MB
  char* ws = (char*)d_ws;
  int* ntiles = (int*)(ws + 0);
  int* tile_e = (int*)(ws + 1024);
  int* tile_r = (int*)(ws + 2048);
  int* perm = (int*)(ws + 4096);                 // 12288 ints
  float* wt = (float*)(ws + 53248);              // 12288 floats
  u16* xb = (u16*)(ws + 131072);                 // [2048][1024] bf16, 4 MB
  u16* WgT = (u16*)(ws + 4325376);               // [E][I][H] bf16, 16 MB
  u16* WuT = (u16*)(ws + 21102592);              // [E][I][H] bf16, 16 MB
  u16* WdT = (u16*)(ws + 37879808);              // [E][H][I] bf16, 16 MB
  u16* ACT = (u16*)(ws + 54657024);              // [MAXROWS][I] bf16, 12 MB

  hipMemsetAsync(out, 0, (size_t)TT * HH * sizeof(float), stream);
  cvt_x_kernel<<<TT * HH / 1024, 256, 0, stream>>>(x, xb);
  transpose_cvt<<<dim3(II / 64, HH / 64, EE), 256, 0, stream>>>(wg, WgT, HH, II);
  transpose_cvt<<<dim3(II / 64, HH / 64, EE), 256, 0, stream>>>(wu, WuT, HH, II);
  transpose_cvt<<<dim3(HH / 64, II / 64, EE), 256, 0, stream>>>(wd, WdT, II, HH);
  route_kernel<<<1, 1024, 0, stream>>>(tidx, tw, perm, wt, tile_e, tile_r, ntiles);
  gemm1_kernel<<<dim3(II / 64, 80), 256, 0, stream>>>(xb, WgT, WuT, perm, wt,
                                                      tile_e, tile_r, ntiles, ACT);
  gemm2_kernel<<<dim3(HH / 128, 80), 256, 0, stream>>>(ACT, WdT, perm,
                                                       tile_e, tile_r, ntiles, out);
}

// Round 3
// 113.771 us; speedup vs baseline: 3.1596x; 1.7328x over previous
//
#include <hip/hip_runtime.h>
#include <hip/hip_bf16.h>
#include <stdint.h>

// Problem constants (from reference): B=1, S=2048, H=1024, I=512, E=16, K=4
#define HH 1024
#define II 512
#define EE 16
#define TT 2048
#define KTOP 4
#define PP (TT * KTOP)      // 8192 routed pairs
#define MAXROWS 12288       // padded row capacity (<= 8192 + 16*127 = 10224 used)

typedef unsigned short u16;
typedef __attribute__((ext_vector_type(8))) short short8;       // bf16 MFMA A/B frag (4 VGPR)
typedef __attribute__((ext_vector_type(4))) float f32x4;        // MFMA C/D frag
typedef __attribute__((ext_vector_type(4))) unsigned short u16x4;
typedef __attribute__((ext_vector_type(8))) unsigned short u16x8;
typedef __attribute__((ext_vector_type(4))) unsigned int u32x4;

__device__ __forceinline__ u16 f2bf(float f) {  // fp32 -> bf16 RNE
  union { float f; unsigned u; } v; v.f = f;
  unsigned r = v.u + 0x7fffu + ((v.u >> 16) & 1u);
  return (u16)(r >> 16);
}
__device__ __forceinline__ float bf2f(u16 b) {
  union { unsigned u; float f; } v; v.u = ((unsigned)b) << 16; return v.f;
}

// LDS chunk swizzle: row stride is 64B (16 banks); XOR the 16B-chunk index with
// row bits so a 16-row b128 frag read covers banks {0,4,...,28} 2-way (free).
#define SWZ(row, c) ((c) ^ (((row) >> 1) & 3))

// ---------------- prep: x fp32 -> bf16 ----------------
__global__ void cvt_x_kernel(const float* __restrict__ x, u16* __restrict__ xb) {
  const int i = (blockIdx.x * 256 + threadIdx.x) * 4;
  f32x4 v = *(const f32x4*)(x + i);
  u16x4 o = { f2bf(v[0]), f2bf(v[1]), f2bf(v[2]), f2bf(v[3]) };
  *(u16x4*)(xb + i) = o;
}

// ---------------- prep: weight [R][C] fp32 -> [C][R] bf16 (per expert z) ----------------
__global__ void transpose_cvt(const float* __restrict__ src, u16* __restrict__ dst,
                              int R, int C) {
  __shared__ u16 tile[64][72];   // +8 pad breaks write/read bank alignment
  const size_t mat = (size_t)blockIdx.z * R * C;
  const int r0 = blockIdx.y * 64, c0 = blockIdx.x * 64;
  const int tid = threadIdx.x;          // 256 threads
  const int row = tid >> 2, cg = (tid & 3) * 16;
  const float* sp = src + mat + (size_t)(r0 + row) * C + c0 + cg;
#pragma unroll
  for (int j = 0; j < 16; j += 4) {
    f32x4 v = *(const f32x4*)(sp + j);
    tile[row][cg + j + 0] = f2bf(v[0]);
    tile[row][cg + j + 1] = f2bf(v[1]);
    tile[row][cg + j + 2] = f2bf(v[2]);
    tile[row][cg + j + 3] = f2bf(v[3]);
  }
  __syncthreads();
  u16* dp = dst + mat + (size_t)(c0 + row) * R + r0 + cg;
  u16x8 o0, o1;
#pragma unroll
  for (int j = 0; j < 8; j++) o0[j] = tile[cg + j][row];
#pragma unroll
  for (int j = 0; j < 8; j++) o1[j] = tile[cg + 8 + j][row];
  *(u16x8*)(dp) = o0;
  *(u16x8*)(dp + 8) = o1;
}

// ---------------- routing: hierarchical deterministic compaction ----------------
// 1 block, 1024 threads (16 waves). Last-duplicate-wins dedup matches the
// reference's scatter-set semantics. Expert lists padded to x128 with
// (token 0, weight 0). Also emits rowof[p] (row index or -1) for the combine.
__global__ __launch_bounds__(1024) void route_kernel(
    const int* __restrict__ tidx, const float* __restrict__ tw,
    int* __restrict__ perm, float* __restrict__ wt, int* __restrict__ rowof,
    int* __restrict__ tile_e, int* __restrict__ tile_r,
    int* __restrict__ ntiles) {
  __shared__ int s_e[PP];          // bits0-3: e, bit4: valid, bits16+: in-segment rank
  __shared__ int whist[16][16];    // [wave][expert] segment counts
  __shared__ int wbase[16][16];    // [wave][expert] global base position
  __shared__ int pad_lo[EE], pad_hi[EE];

  const int tid = threadIdx.x;
  const int lane = tid & 63;
  const int wv = tid >> 6;

  // Phase 1: load topk_idx (int4 per token), validity, pack to LDS
#pragma unroll
  for (int i = 0; i < 2; i++) {
    const int t = tid + i * 1024;
    const int4 v = ((const int4*)tidx)[t];
    const bool v0 = (v.x != v.y) && (v.x != v.z) && (v.x != v.w);
    const bool v1 = (v.y != v.z) && (v.y != v.w);
    const bool v2 = (v.z != v.w);
    s_e[t * 4 + 0] = v.x | (v0 ? 16 : 0);
    s_e[t * 4 + 1] = v.y | (v1 ? 16 : 0);
    s_e[t * 4 + 2] = v.z | (v2 ? 16 : 0);
    s_e[t * 4 + 3] = v.w | 16;
  }
  __syncthreads();

  // Phase 2: per-wave in-order ranking of its 512-pair segment
  int h0, h1, h2, h3, h4, h5, h6, h7, h8, h9, h10, h11, h12, h13, h14, h15;
  h0=h1=h2=h3=h4=h5=h6=h7=h8=h9=h10=h11=h12=h13=h14=h15=0;
  const unsigned long long ltm = (1ull << lane) - 1ull;
  for (int c = 0; c < 8; c++) {
    const int p = (wv << 9) + (c << 6) + lane;
    const int se = s_e[p];
    const int e = se & 15;
    const bool valid = (se & 16) != 0;
    int rank = 0;
#define RANK_STEP(J, HJ)                                            \
    {                                                               \
      unsigned long long m = __ballot(valid && (e == J));           \
      if (valid && (e == J)) rank = HJ + __popcll(m & ltm);         \
      HJ += __popcll(m);                                            \
    }
    RANK_STEP(0, h0)  RANK_STEP(1, h1)  RANK_STEP(2, h2)  RANK_STEP(3, h3)
    RANK_STEP(4, h4)  RANK_STEP(5, h5)  RANK_STEP(6, h6)  RANK_STEP(7, h7)
    RANK_STEP(8, h8)  RANK_STEP(9, h9)  RANK_STEP(10, h10) RANK_STEP(11, h11)
    RANK_STEP(12, h12) RANK_STEP(13, h13) RANK_STEP(14, h14) RANK_STEP(15, h15)
#undef RANK_STEP
    if (valid) s_e[p] = se | (rank << 16);
  }
  if (lane == 0) {
    whist[wv][0] = h0;   whist[wv][1] = h1;   whist[wv][2] = h2;   whist[wv][3] = h3;
    whist[wv][4] = h4;   whist[wv][5] = h5;   whist[wv][6] = h6;   whist[wv][7] = h7;
    whist[wv][8] = h8;   whist[wv][9] = h9;   whist[wv][10] = h10; whist[wv][11] = h11;
    whist[wv][12] = h12; whist[wv][13] = h13; whist[wv][14] = h14; whist[wv][15] = h15;
  }
  __syncthreads();

  // Phase 3: tiny scan -> per-(wave,expert) bases, tile table, pad ranges
  if (tid == 0) {
    int off = 0, nt = 0;
    for (int j = 0; j < EE; j++) {
      int tot = 0;
      for (int w = 0; w < 16; w++) { wbase[w][j] = off + tot; tot += whist[w][j]; }
      const int cap = (tot + 127) & ~127;
      pad_lo[j] = off + tot;
      pad_hi[j] = off + cap;
      for (int m0 = 0; m0 < cap; m0 += 128) { tile_e[nt] = j; tile_r[nt] = off + m0; nt++; }
      off += cap;
    }
    *ntiles = nt;
  }
  __syncthreads();

  // Phase 4: scatter perm/wt/rowof (coalesced tw reads), then pad fill
#pragma unroll
  for (int i = 0; i < 8; i++) {
    const int p = i * 1024 + tid;
    const int se = s_e[p];
    int pos = -1;
    if (se & 16) {
      const int e = se & 15;
      const int r = se >> 16;
      pos = wbase[p >> 9][e] + r;
      perm[pos] = p >> 2;
      wt[pos] = tw[p];
    }
    rowof[p] = pos;
  }
  for (int j = 0; j < EE; j++) {
    const int lo = pad_lo[j], hi = pad_hi[j];
    for (int i = lo + tid; i < hi; i += 1024) {
      perm[i] = 0;          // pad: token 0 with weight 0 contributes exactly nothing
      wt[i] = 0.f;
    }
  }
}

// ---------------- GEMM1: ACT[r][i] = silu(x@Wg) * (x@Wu) * gate_weight, bf16 ----------------
// Tile 128(M) x 64(N), BK=32, 4 waves as 2x2; each wave 64x32 = 4x2 MFMA frags, dual acc.
__global__ __launch_bounds__(256) void gemm1_kernel(
    const u16* __restrict__ xb, const u16* __restrict__ WgT, const u16* __restrict__ WuT,
    const int* __restrict__ perm, const float* __restrict__ wt,
    const int* __restrict__ tile_e, const int* __restrict__ tile_r,
    const int* __restrict__ ntiles, u16* __restrict__ ACT) {
  const int tileid = blockIdx.y;
  if (tileid >= *ntiles) return;
  const int e = tile_e[tileid];
  const int row0 = tile_r[tileid];
  const int n0 = blockIdx.x * 64;

  __shared__ __align__(16) u16 As[128 * 32];
  __shared__ __align__(16) u16 Gs[64 * 32];
  __shared__ __align__(16) u16 Us[64 * 32];

  const int tid = threadIdx.x;
  const int lane = tid & 63;
  const int wid = tid >> 6;
  const int wm = wid >> 1, wn = wid & 1;
  const int fr = lane & 15, fq = lane >> 4;

  const int srow = tid >> 2;             // 0..63
  const int chnk = tid & 3;              // 16B chunk 0..3
  const int scol = chnk * 8;

  const int tok0 = perm[row0 + srow];
  const int tok1 = perm[row0 + 64 + srow];
  const size_t aoff0 = (size_t)tok0 * HH + scol;
  const size_t aoff1 = (size_t)tok1 * HH + scol;
  const size_t boff = ((size_t)e * II + n0 + srow) * HH + scol;

  f32x4 accg[4][2], accu[4][2];
  const f32x4 vz = {0.f, 0.f, 0.f, 0.f};
#pragma unroll
  for (int m = 0; m < 4; m++)
#pragma unroll
    for (int n = 0; n < 2; n++) { accg[m][n] = vz; accu[m][n] = vz; }

  for (int k0 = 0; k0 < HH; k0 += 32) {
    u32x4 a0 = *(const u32x4*)(xb + aoff0 + k0);
    u32x4 a1 = *(const u32x4*)(xb + aoff1 + k0);
    u32x4 g0 = *(const u32x4*)(WgT + boff + k0);
    u32x4 u0 = *(const u32x4*)(WuT + boff + k0);
    __syncthreads();
    *(u32x4*)(&As[srow * 32 + SWZ(srow, chnk) * 8]) = a0;
    *(u32x4*)(&As[(64 + srow) * 32 + SWZ(64 + srow, chnk) * 8]) = a1;
    *(u32x4*)(&Gs[srow * 32 + SWZ(srow, chnk) * 8]) = g0;
    *(u32x4*)(&Us[srow * 32 + SWZ(srow, chnk) * 8]) = u0;
    __syncthreads();

    short8 af[4], bg[2], bu[2];
#pragma unroll
    for (int m = 0; m < 4; m++) {
      const int r = wm * 64 + m * 16 + fr;
      af[m] = *(const short8*)(&As[r * 32 + SWZ(r, fq) * 8]);
    }
#pragma unroll
    for (int n = 0; n < 2; n++) {
      const int r = wn * 32 + n * 16 + fr;
      bg[n] = *(const short8*)(&Gs[r * 32 + SWZ(r, fq) * 8]);
      bu[n] = *(const short8*)(&Us[r * 32 + SWZ(r, fq) * 8]);
    }
#pragma unroll
    for (int m = 0; m < 4; m++)
#pragma unroll
      for (int n = 0; n < 2; n++) {
        accg[m][n] = __builtin_amdgcn_mfma_f32_16x16x32_bf16(af[m], bg[n], accg[m][n], 0, 0, 0);
        accu[m][n] = __builtin_amdgcn_mfma_f32_16x16x32_bf16(af[m], bu[n], accu[m][n], 0, 0, 0);
      }
  }

  // C/D layout: col = lane&15, row = (lane>>4)*4 + j
#pragma unroll
  for (int m = 0; m < 4; m++) {
    const int rbase = wm * 64 + m * 16 + fq * 4;
#pragma unroll
    for (int j = 0; j < 4; j++) {
      const int rloc = rbase + j;
      const float w = wt[row0 + rloc];
#pragma unroll
      for (int n = 0; n < 2; n++) {
        const float g = accg[m][n][j];
        const float u = accu[m][n][j];
        const float s = g / (1.f + __expf(-g));   // silu
        ACT[(size_t)(row0 + rloc) * II + n0 + (wn * 32 + n * 16 + fr)] = f2bf(s * u * w);
      }
    }
  }
}

// ---------------- GEMM2: D[row][h] = ACT @ Wd  (bf16 staging, plain stores) ----------------
// Tile 128(M) x 128(N), BK=32, 4 waves as 2x2; each wave 64x64 = 4x4 frags.
__global__ __launch_bounds__(256) void gemm2_kernel(
    const u16* __restrict__ ACT, const u16* __restrict__ WdT,
    const int* __restrict__ tile_e, const int* __restrict__ tile_r,
    const int* __restrict__ ntiles, u16* __restrict__ D) {
  const int tileid = blockIdx.y;
  if (tileid >= *ntiles) return;
  const int e = tile_e[tileid];
  const int row0 = tile_r[tileid];
  const int n0 = blockIdx.x * 128;

  __shared__ __align__(16) u16 As[128 * 32];
  __shared__ __align__(16) u16 Bs[128 * 32];

  const int tid = threadIdx.x;
  const int lane = tid & 63;
  const int wid = tid >> 6;
  const int wm = wid >> 1, wn = wid & 1;
  const int fr = lane & 15, fq = lane >> 4;

  const int srow = tid >> 2;
  const int chnk = tid & 3;
  const int scol = chnk * 8;

  const size_t aoff0 = (size_t)(row0 + srow) * II + scol;
  const size_t aoff1 = (size_t)(row0 + 64 + srow) * II + scol;
  const size_t boff0 = ((size_t)e * HH + n0 + srow) * II + scol;
  const size_t boff1 = ((size_t)e * HH + n0 + 64 + srow) * II + scol;

  f32x4 acc[4][4];
  const f32x4 vz = {0.f, 0.f, 0.f, 0.f};
#pragma unroll
  for (int m = 0; m < 4; m++)
#pragma unroll
    for (int n = 0; n < 4; n++) acc[m][n] = vz;

  for (int k0 = 0; k0 < II; k0 += 32) {
    u32x4 a0 = *(const u32x4*)(ACT + aoff0 + k0);
    u32x4 a1 = *(const u32x4*)(ACT + aoff1 + k0);
    u32x4 b0 = *(const u32x4*)(WdT + boff0 + k0);
    u32x4 b1 = *(const u32x4*)(WdT + boff1 + k0);
    __syncthreads();
    *(u32x4*)(&As[srow * 32 + SWZ(srow, chnk) * 8]) = a0;
    *(u32x4*)(&As[(64 + srow) * 32 + SWZ(64 + srow, chnk) * 8]) = a1;
    *(u32x4*)(&Bs[srow * 32 + SWZ(srow, chnk) * 8]) = b0;
    *(u32x4*)(&Bs[(64 + srow) * 32 + SWZ(64 + srow, chnk) * 8]) = b1;
    __syncthreads();

    short8 af[4], bf[4];
#pragma unroll
    for (int m = 0; m < 4; m++) {
      const int r = wm * 64 + m * 16 + fr;
      af[m] = *(const short8*)(&As[r * 32 + SWZ(r, fq) * 8]);
    }
#pragma unroll
    for (int n = 0; n < 4; n++) {
      const int r = wn * 64 + n * 16 + fr;
      bf[n] = *(const short8*)(&Bs[r * 32 + SWZ(r, fq) * 8]);
    }
#pragma unroll
    for (int m = 0; m < 4; m++)
#pragma unroll
      for (int n = 0; n < 4; n++)
        acc[m][n] = __builtin_amdgcn_mfma_f32_16x16x32_bf16(af[m], bf[n], acc[m][n], 0, 0, 0);
  }

#pragma unroll
  for (int m = 0; m < 4; m++) {
    const int rbase = wm * 64 + m * 16 + fq * 4;
#pragma unroll
    for (int j = 0; j < 4; j++) {
      u16* dp = D + (size_t)(row0 + rbase + j) * HH + n0 + wn * 64 + fr;
#pragma unroll
      for (int n = 0; n < 4; n++)
        dp[n * 16] = f2bf(acc[m][n][j]);
    }
  }
}

// ---------------- combine: out[t][h] = sum over t's valid pairs of D[row][h] ----------------
__global__ __launch_bounds__(256) void combine_kernel(
    const u16* __restrict__ D, const int* __restrict__ rowof,
    float* __restrict__ out) {
  const int t = blockIdx.x;
  const int h = threadIdx.x * 4;
  const int4 r4 = ((const int4*)rowof)[t];
  float a0 = 0.f, a1 = 0.f, a2 = 0.f, a3 = 0.f;
#define ACCUM(R)                                                     \
  if ((R) >= 0) {                                                    \
    u16x4 d = *(const u16x4*)(D + (size_t)(R) * HH + h);             \
    a0 += bf2f(d[0]); a1 += bf2f(d[1]); a2 += bf2f(d[2]); a3 += bf2f(d[3]); \
  }
  ACCUM(r4.x) ACCUM(r4.y) ACCUM(r4.z) ACCUM(r4.w)
#undef ACCUM
  float4 o = { a0, a1, a2, a3 };
  *(float4*)(out + (size_t)t * HH + h) = o;
}

// ---------------- launch ----------------
extern "C" void kernel_launch(void* const* d_in, const int* in_sizes, int n_in,
                              void* d_out, int out_size, void* d_ws, size_t ws_size,
                              hipStream_t stream) {
  const float* x = (const float*)d_in[0];
  const int* tidx = (const int*)d_in[1];
  const float* tw = (const float*)d_in[2];
  const float* wg = (const float*)d_in[3];
  const float* wu = (const float*)d_in[4];
  const float* wd = (const float*)d_in[5];
  float* out = (float*)d_out;

  // ws layout (bytes); total ~64.3 MB. D overlays WgT/WuT (dead after gemm1).
  char* ws = (char*)d_ws;
  int* ntiles = (int*)(ws + 0);
  int* tile_e = (int*)(ws + 1024);
  int* tile_r = (int*)(ws + 2048);
  int* perm = (int*)(ws + 4096);                 // 12288 ints -> ends 53248
  float* wt = (float*)(ws + 53248);              // 12288 floats -> ends 102400
  int* rowof = (int*)(ws + 102400);              // 8192 ints -> ends 135168
  u16* xb = (u16*)(ws + 262144);                 // [2048][1024] bf16, 4 MB
  u16* WgT = (u16*)(ws + 4456448);               // [E][I][H] bf16, 16.78 MB
  u16* WuT = (u16*)(ws + 21233664);              // [E][I][H] bf16, 16.78 MB
  u16* WdT = (u16*)(ws + 38010880);              // [E][H][I] bf16, 16.78 MB
  u16* ACT = (u16*)(ws + 54788096);              // [MAXROWS][I] bf16, 12.58 MB
  u16* D = (u16*)(ws + 4456448);                 // [MAXROWS][H] bf16, 25.2 MB (overlay)

  cvt_x_kernel<<<TT * HH / 1024, 256, 0, stream>>>(x, xb);
  transpose_cvt<<<dim3(II / 64, HH / 64, EE), 256, 0, stream>>>(wg, WgT, HH, II);
  transpose_cvt<<<dim3(II / 64, HH / 64, EE), 256, 0, stream>>>(wu, WuT, HH, II);
  transpose_cvt<<<dim3(HH / 64, II / 64, EE), 256, 0, stream>>>(wd, WdT, II, HH);
  route_kernel<<<1, 1024, 0, stream>>>(tidx, tw, perm, wt, rowof, tile_e, tile_r, ntiles);
  gemm1_kernel<<<dim3(II / 64, 80), 256, 0, stream>>>(xb, WgT, WuT, perm, wt,
                                                      tile_e, tile_r, ntiles, ACT);
  gemm2_kernel<<<dim3(HH / 128, 80), 256, 0, stream>>>(ACT, WdT,
                                                       tile_e, tile_r, ntiles, D);
  combine_kernel<<<TT, 256, 0, stream>>>(D, rowof, out);
}

// Round 4
// 109.909 us; speedup vs baseline: 3.2706x; 1.0351x over previous
//
#include <hip/hip_runtime.h>
#include <hip/hip_bf16.h>
#include <stdint.h>

// Problem constants (from reference): B=1, S=2048, H=1024, I=512, E=16, K=4
#define HH 1024
#define II 512
#define EE 16
#define TT 2048
#define KTOP 4
#define PP (TT * KTOP)      // 8192 routed pairs
#define MAXROWS 12288       // padded row capacity (<= 8192 + 16*127 = 10224 used)

typedef unsigned short u16;
typedef __attribute__((ext_vector_type(8))) short short8;       // bf16 MFMA A/B frag (4 VGPR)
typedef __attribute__((ext_vector_type(4))) float f32x4;        // MFMA C/D frag
typedef __attribute__((ext_vector_type(4))) unsigned short u16x4;
typedef __attribute__((ext_vector_type(8))) unsigned short u16x8;
typedef __attribute__((ext_vector_type(4))) unsigned int u32x4;

__device__ __forceinline__ u16 f2bf(float f) {  // fp32 -> bf16 RNE
  union { float f; unsigned u; } v; v.f = f;
  unsigned r = v.u + 0x7fffu + ((v.u >> 16) & 1u);
  return (u16)(r >> 16);
}
__device__ __forceinline__ float bf2f(u16 b) {
  union { unsigned u; float f; } v; v.u = ((unsigned)b) << 16; return v.f;
}

// LDS chunk swizzle (read side): row stride 64B; XOR 16B-chunk index with row
// bits so a 16-row b128 frag read covers all 32 banks 2-way (free).
#define SWZ(row, c) ((c) ^ (((row) >> 1) & 3))

// Direct global->LDS DMA, 16B per lane. LDS dest is wave-uniform base + lane*16
// (linear); the swizzle is applied on the per-lane GLOBAL source address.
__device__ __forceinline__ void gld16(const u16* g, u16* l) {
  __builtin_amdgcn_global_load_lds(
      (const __attribute__((address_space(1))) unsigned int*)g,
      (__attribute__((address_space(3))) unsigned int*)l, 16, 0, 0);
}

// ---------------- prep: x fp32 -> bf16 ----------------
__global__ void cvt_x_kernel(const float* __restrict__ x, u16* __restrict__ xb) {
  const int i = (blockIdx.x * 256 + threadIdx.x) * 4;
  f32x4 v = *(const f32x4*)(x + i);
  u16x4 o = { f2bf(v[0]), f2bf(v[1]), f2bf(v[2]), f2bf(v[3]) };
  *(u16x4*)(xb + i) = o;
}

// ---------------- prep: all 3 weights, [R][C] fp32 -> [C][R] bf16 per expert ----------------
// Flat grid of 6144 64x64 tiles: [0,2048) wg, [2048,4096) wu, [4096,6144) wd.
__global__ __launch_bounds__(256) void prep_weights(
    const float* __restrict__ wg, const float* __restrict__ wu, const float* __restrict__ wd,
    u16* __restrict__ WgT, u16* __restrict__ WuT, u16* __restrict__ WdT) {
  __shared__ u16 tile[64][72];   // +8 pad breaks write/read bank alignment
  const int bid = blockIdx.x;
  const int matsel = bid >> 11;
  const int within = bid & 2047;
  const float* src; u16* dst; int R, C, xi, yi;
  if (matsel == 0)      { src = wg; dst = WgT; R = HH; C = II; xi = within & 7;  yi = (within >> 3) & 15; }
  else if (matsel == 1) { src = wu; dst = WuT; R = HH; C = II; xi = within & 7;  yi = (within >> 3) & 15; }
  else                  { src = wd; dst = WdT; R = II; C = HH; xi = within & 15; yi = (within >> 4) & 7;  }
  const int zz = within >> 7;
  const size_t mat = (size_t)zz * R * C;
  const int r0 = yi * 64, c0 = xi * 64;
  const int tid = threadIdx.x;
  const int row = tid >> 2, cg = (tid & 3) * 16;
  const float* sp = src + mat + (size_t)(r0 + row) * C + c0 + cg;
#pragma unroll
  for (int j = 0; j < 16; j += 4) {
    f32x4 v = *(const f32x4*)(sp + j);
    tile[row][cg + j + 0] = f2bf(v[0]);
    tile[row][cg + j + 1] = f2bf(v[1]);
    tile[row][cg + j + 2] = f2bf(v[2]);
    tile[row][cg + j + 3] = f2bf(v[3]);
  }
  __syncthreads();
  u16* dp = dst + mat + (size_t)(c0 + row) * R + r0 + cg;
  u16x8 o0, o1;
#pragma unroll
  for (int j = 0; j < 8; j++) o0[j] = tile[cg + j][row];
#pragma unroll
  for (int j = 0; j < 8; j++) o1[j] = tile[cg + 8 + j][row];
  *(u16x8*)(dp) = o0;
  *(u16x8*)(dp + 8) = o1;
}

// ---------------- routing: hierarchical deterministic compaction ----------------
// 1 block, 1024 threads (16 waves). Last-duplicate-wins dedup matches the
// reference's scatter-set semantics. Expert lists padded to x128 with
// (token 0, weight 0). Also emits rowof[p] (row index or -1) for the combine.
__global__ __launch_bounds__(1024) void route_kernel(
    const int* __restrict__ tidx, const float* __restrict__ tw,
    int* __restrict__ perm, float* __restrict__ wt, int* __restrict__ rowof,
    int* __restrict__ tile_e, int* __restrict__ tile_r,
    int* __restrict__ ntiles) {
  __shared__ int s_e[PP];          // bits0-3: e, bit4: valid, bits16+: in-segment rank
  __shared__ int whist[16][16];    // [wave][expert] segment counts
  __shared__ int wbase[16][16];    // [wave][expert] global base position
  __shared__ int pad_lo[EE], pad_hi[EE];

  const int tid = threadIdx.x;
  const int lane = tid & 63;
  const int wv = tid >> 6;

  // Phase 1: load topk_idx (int4 per token), validity, pack to LDS
#pragma unroll
  for (int i = 0; i < 2; i++) {
    const int t = tid + i * 1024;
    const int4 v = ((const int4*)tidx)[t];
    const bool v0 = (v.x != v.y) && (v.x != v.z) && (v.x != v.w);
    const bool v1 = (v.y != v.z) && (v.y != v.w);
    const bool v2 = (v.z != v.w);
    s_e[t * 4 + 0] = v.x | (v0 ? 16 : 0);
    s_e[t * 4 + 1] = v.y | (v1 ? 16 : 0);
    s_e[t * 4 + 2] = v.z | (v2 ? 16 : 0);
    s_e[t * 4 + 3] = v.w | 16;
  }
  __syncthreads();

  // Phase 2: per-wave in-order ranking of its 512-pair segment
  int h0, h1, h2, h3, h4, h5, h6, h7, h8, h9, h10, h11, h12, h13, h14, h15;
  h0=h1=h2=h3=h4=h5=h6=h7=h8=h9=h10=h11=h12=h13=h14=h15=0;
  const unsigned long long ltm = (1ull << lane) - 1ull;
  for (int c = 0; c < 8; c++) {
    const int p = (wv << 9) + (c << 6) + lane;
    const int se = s_e[p];
    const int e = se & 15;
    const bool valid = (se & 16) != 0;
    int rank = 0;
#define RANK_STEP(J, HJ)                                            \
    {                                                               \
      unsigned long long m = __ballot(valid && (e == J));           \
      if (valid && (e == J)) rank = HJ + __popcll(m & ltm);         \
      HJ += __popcll(m);                                            \
    }
    RANK_STEP(0, h0)  RANK_STEP(1, h1)  RANK_STEP(2, h2)  RANK_STEP(3, h3)
    RANK_STEP(4, h4)  RANK_STEP(5, h5)  RANK_STEP(6, h6)  RANK_STEP(7, h7)
    RANK_STEP(8, h8)  RANK_STEP(9, h9)  RANK_STEP(10, h10) RANK_STEP(11, h11)
    RANK_STEP(12, h12) RANK_STEP(13, h13) RANK_STEP(14, h14) RANK_STEP(15, h15)
#undef RANK_STEP
    if (valid) s_e[p] = se | (rank << 16);
  }
  if (lane == 0) {
    whist[wv][0] = h0;   whist[wv][1] = h1;   whist[wv][2] = h2;   whist[wv][3] = h3;
    whist[wv][4] = h4;   whist[wv][5] = h5;   whist[wv][6] = h6;   whist[wv][7] = h7;
    whist[wv][8] = h8;   whist[wv][9] = h9;   whist[wv][10] = h10; whist[wv][11] = h11;
    whist[wv][12] = h12; whist[wv][13] = h13; whist[wv][14] = h14; whist[wv][15] = h15;
  }
  __syncthreads();

  // Phase 3: tiny scan -> per-(wave,expert) bases, tile table, pad ranges
  if (tid == 0) {
    int off = 0, nt = 0;
    for (int j = 0; j < EE; j++) {
      int tot = 0;
      for (int w = 0; w < 16; w++) { wbase[w][j] = off + tot; tot += whist[w][j]; }
      const int cap = (tot + 127) & ~127;
      pad_lo[j] = off + tot;
      pad_hi[j] = off + cap;
      for (int m0 = 0; m0 < cap; m0 += 128) { tile_e[nt] = j; tile_r[nt] = off + m0; nt++; }
      off += cap;
    }
    *ntiles = nt;
  }
  __syncthreads();

  // Phase 4: scatter perm/wt/rowof (coalesced tw reads), then pad fill
#pragma unroll
  for (int i = 0; i < 8; i++) {
    const int p = i * 1024 + tid;
    const int se = s_e[p];
    int pos = -1;
    if (se & 16) {
      const int e = se & 15;
      const int r = se >> 16;
      pos = wbase[p >> 9][e] + r;
      perm[pos] = p >> 2;
      wt[pos] = tw[p];
    }
    rowof[p] = pos;
  }
  for (int j = 0; j < EE; j++) {
    const int lo = pad_lo[j], hi = pad_hi[j];
    for (int i = lo + tid; i < hi; i += 1024) {
      perm[i] = 0;          // pad: token 0 with weight 0 contributes exactly nothing
      wt[i] = 0.f;
    }
  }
}

// ---------------- GEMM1: ACT[r][i] = silu(x@Wg) * (x@Wu) * gate_weight, bf16 ----------------
// Tile 128(M) x 64(N), BK=32, 4 waves as 2x2. Staging via global_load_lds:
// linear LDS dest, swizzle folded into the per-lane global source chunk.
__global__ __launch_bounds__(256) void gemm1_kernel(
    const u16* __restrict__ xb, const u16* __restrict__ WgT, const u16* __restrict__ WuT,
    const int* __restrict__ perm, const float* __restrict__ wt,
    const int* __restrict__ tile_e, const int* __restrict__ tile_r,
    const int* __restrict__ ntiles, u16* __restrict__ ACT) {
  const int tileid = blockIdx.y;
  if (tileid >= *ntiles) return;
  const int e = tile_e[tileid];
  const int row0 = tile_r[tileid];
  const int n0 = blockIdx.x * 64;

  __shared__ __align__(16) u16 As[128 * 32];
  __shared__ __align__(16) u16 Gs[64 * 32];
  __shared__ __align__(16) u16 Us[64 * 32];

  const int tid = threadIdx.x;
  const int lane = tid & 63;
  const int wid = tid >> 6;
  const int wm = wid >> 1, wn = wid & 1;
  const int fr = lane & 15, fq = lane >> 4;

  const int srow = tid >> 2;                       // 0..63
  const int swzc = (tid & 3) ^ ((srow >> 1) & 3);  // pre-swizzled source chunk

  const int tok0 = perm[row0 + srow];
  const int tok1 = perm[row0 + 64 + srow];
  const u16* gA0 = xb + (size_t)tok0 * HH + swzc * 8;
  const u16* gA1 = xb + (size_t)tok1 * HH + swzc * 8;  // rows 64+srow: same swzc (bit5 of row doesn't enter SWZ)
  const u16* gG  = WgT + ((size_t)e * II + n0 + srow) * HH + swzc * 8;
  const u16* gU  = WuT + ((size_t)e * II + n0 + srow) * HH + swzc * 8;
  u16* lA0 = As + wid * 512;          // chunks [wid*64, wid*64+64)
  u16* lA1 = As + 2048 + wid * 512;   // chunks [256+wid*64, ...)
  u16* lG  = Gs + wid * 512;
  u16* lU  = Us + wid * 512;

  f32x4 accg[4][2], accu[4][2];
  const f32x4 vz = {0.f, 0.f, 0.f, 0.f};
#pragma unroll
  for (int m = 0; m < 4; m++)
#pragma unroll
    for (int n = 0; n < 2; n++) { accg[m][n] = vz; accu[m][n] = vz; }

  for (int k0 = 0; k0 < HH; k0 += 32) {
    __syncthreads();                   // previous iteration's reads complete
    gld16(gA0 + k0, lA0);
    gld16(gA1 + k0, lA1);
    gld16(gG + k0, lG);
    gld16(gU + k0, lU);
    __syncthreads();                   // compiler drains vmcnt before barrier

    short8 af[4], bg[2], bu[2];
#pragma unroll
    for (int m = 0; m < 4; m++) {
      const int r = wm * 64 + m * 16 + fr;
      af[m] = *(const short8*)(&As[r * 32 + SWZ(r, fq) * 8]);
    }
#pragma unroll
    for (int n = 0; n < 2; n++) {
      const int r = wn * 32 + n * 16 + fr;
      bg[n] = *(const short8*)(&Gs[r * 32 + SWZ(r, fq) * 8]);
      bu[n] = *(const short8*)(&Us[r * 32 + SWZ(r, fq) * 8]);
    }
#pragma unroll
    for (int m = 0; m < 4; m++)
#pragma unroll
      for (int n = 0; n < 2; n++) {
        accg[m][n] = __builtin_amdgcn_mfma_f32_16x16x32_bf16(af[m], bg[n], accg[m][n], 0, 0, 0);
        accu[m][n] = __builtin_amdgcn_mfma_f32_16x16x32_bf16(af[m], bu[n], accu[m][n], 0, 0, 0);
      }
  }

  // C/D layout: col = lane&15, row = (lane>>4)*4 + j
#pragma unroll
  for (int m = 0; m < 4; m++) {
    const int rbase = wm * 64 + m * 16 + fq * 4;
#pragma unroll
    for (int j = 0; j < 4; j++) {
      const int rloc = rbase + j;
      const float w = wt[row0 + rloc];
#pragma unroll
      for (int n = 0; n < 2; n++) {
        const float g = accg[m][n][j];
        const float u = accu[m][n][j];
        const float s = g / (1.f + __expf(-g));   // silu
        ACT[(size_t)(row0 + rloc) * II + n0 + (wn * 32 + n * 16 + fr)] = f2bf(s * u * w);
      }
    }
  }
}

// ---------------- GEMM2: D[row][h] = ACT @ Wd  (bf16 staging, plain stores) ----------------
// Tile 128(M) x 128(N), BK=32, 4 waves as 2x2; global_load_lds staging.
__global__ __launch_bounds__(256) void gemm2_kernel(
    const u16* __restrict__ ACT, const u16* __restrict__ WdT,
    const int* __restrict__ tile_e, const int* __restrict__ tile_r,
    const int* __restrict__ ntiles, u16* __restrict__ D) {
  const int tileid = blockIdx.y;
  if (tileid >= *ntiles) return;
  const int e = tile_e[tileid];
  const int row0 = tile_r[tileid];
  const int n0 = blockIdx.x * 128;

  __shared__ __align__(16) u16 As[128 * 32];
  __shared__ __align__(16) u16 Bs[128 * 32];

  const int tid = threadIdx.x;
  const int lane = tid & 63;
  const int wid = tid >> 6;
  const int wm = wid >> 1, wn = wid & 1;
  const int fr = lane & 15, fq = lane >> 4;

  const int srow = tid >> 2;
  const int swzc = (tid & 3) ^ ((srow >> 1) & 3);

  const u16* gA0 = ACT + (size_t)(row0 + srow) * II + swzc * 8;
  const u16* gA1 = ACT + (size_t)(row0 + 64 + srow) * II + swzc * 8;
  const u16* gB0 = WdT + ((size_t)e * HH + n0 + srow) * II + swzc * 8;
  const u16* gB1 = WdT + ((size_t)e * HH + n0 + 64 + srow) * II + swzc * 8;
  u16* lA0 = As + wid * 512;
  u16* lA1 = As + 2048 + wid * 512;
  u16* lB0 = Bs + wid * 512;
  u16* lB1 = Bs + 2048 + wid * 512;

  f32x4 acc[4][4];
  const f32x4 vz = {0.f, 0.f, 0.f, 0.f};
#pragma unroll
  for (int m = 0; m < 4; m++)
#pragma unroll
    for (int n = 0; n < 4; n++) acc[m][n] = vz;

  for (int k0 = 0; k0 < II; k0 += 32) {
    __syncthreads();
    gld16(gA0 + k0, lA0);
    gld16(gA1 + k0, lA1);
    gld16(gB0 + k0, lB0);
    gld16(gB1 + k0, lB1);
    __syncthreads();

    short8 af[4], bf[4];
#pragma unroll
    for (int m = 0; m < 4; m++) {
      const int r = wm * 64 + m * 16 + fr;
      af[m] = *(const short8*)(&As[r * 32 + SWZ(r, fq) * 8]);
    }
#pragma unroll
    for (int n = 0; n < 4; n++) {
      const int r = wn * 64 + n * 16 + fr;
      bf[n] = *(const short8*)(&Bs[r * 32 + SWZ(r, fq) * 8]);
    }
#pragma unroll
    for (int m = 0; m < 4; m++)
#pragma unroll
      for (int n = 0; n < 4; n++)
        acc[m][n] = __builtin_amdgcn_mfma_f32_16x16x32_bf16(af[m], bf[n], acc[m][n], 0, 0, 0);
  }

#pragma unroll
  for (int m = 0; m < 4; m++) {
    const int rbase = wm * 64 + m * 16 + fq * 4;
#pragma unroll
    for (int j = 0; j < 4; j++) {
      u16* dp = D + (size_t)(row0 + rbase + j) * HH + n0 + wn * 64 + fr;
#pragma unroll
      for (int n = 0; n < 4; n++)
        dp[n * 16] = f2bf(acc[m][n][j]);
    }
  }
}

// ---------------- combine: out[t][h] = sum over t's valid pairs of D[row][h] ----------------
__global__ __launch_bounds__(256) void combine_kernel(
    const u16* __restrict__ D, const int* __restrict__ rowof,
    float* __restrict__ out) {
  const int t = blockIdx.x;
  const int h = threadIdx.x * 4;
  const int4 r4 = ((const int4*)rowof)[t];
  float a0 = 0.f, a1 = 0.f, a2 = 0.f, a3 = 0.f;
#define ACCUM(R)                                                     \
  if ((R) >= 0) {                                                    \
    u16x4 d = *(const u16x4*)(D + (size_t)(R) * HH + h);             \
    a0 += bf2f(d[0]); a1 += bf2f(d[1]); a2 += bf2f(d[2]); a3 += bf2f(d[3]); \
  }
  ACCUM(r4.x) ACCUM(r4.y) ACCUM(r4.z) ACCUM(r4.w)
#undef ACCUM
  float4 o = { a0, a1, a2, a3 };
  *(float4*)(out + (size_t)t * HH + h) = o;
}

// ---------------- launch ----------------
extern "C" void kernel_launch(void* const* d_in, const int* in_sizes, int n_in,
                              void* d_out, int out_size, void* d_ws, size_t ws_size,
                              hipStream_t stream) {
  const float* x = (const float*)d_in[0];
  const int* tidx = (const int*)d_in[1];
  const float* tw = (const float*)d_in[2];
  const float* wg = (const float*)d_in[3];
  const float* wu = (const float*)d_in[4];
  const float* wd = (const float*)d_in[5];
  float* out = (float*)d_out;

  // ws layout (bytes); total ~67 MB. D overlays WgT/WuT (dead after gemm1).
  char* ws = (char*)d_ws;
  int* ntiles = (int*)(ws + 0);
  int* tile_e = (int*)(ws + 1024);
  int* tile_r = (int*)(ws + 2048);
  int* perm = (int*)(ws + 4096);                 // 12288 ints -> ends 53248
  float* wt = (float*)(ws + 53248);              // 12288 floats -> ends 102400
  int* rowof = (int*)(ws + 102400);              // 8192 ints -> ends 135168
  u16* xb = (u16*)(ws + 262144);                 // [2048][1024] bf16, 4 MB
  u16* WgT = (u16*)(ws + 4456448);               // [E][I][H] bf16, 16.78 MB
  u16* WuT = (u16*)(ws + 21233664);              // [E][I][H] bf16, 16.78 MB
  u16* WdT = (u16*)(ws + 38010880);               // [E][H][I] bf16, 16.78 MB
  u16* ACT = (u16*)(ws + 54788096);              // [MAXROWS][I] bf16, 12.58 MB
  u16* D = (u16*)(ws + 4456448);                 // [MAXROWS][H] bf16, 25.2 MB (overlay)

  cvt_x_kernel<<<TT * HH / 1024, 256, 0, stream>>>(x, xb);
  prep_weights<<<6144, 256, 0, stream>>>(wg, wu, wd, WgT, WuT, WdT);
  route_kernel<<<1, 1024, 0, stream>>>(tidx, tw, perm, wt, rowof, tile_e, tile_r, ntiles);
  gemm1_kernel<<<dim3(II / 64, 80), 256, 0, stream>>>(xb, WgT, WuT, perm, wt,
                                                      tile_e, tile_r, ntiles, ACT);
  gemm2_kernel<<<dim3(HH / 128, 80), 256, 0, stream>>>(ACT, WdT,
                                                       tile_e, tile_r, ntiles, D);
  combine_kernel<<<TT, 256, 0, stream>>>(D, rowof, out);
}

// Round 5
// 102.482 us; speedup vs baseline: 3.5077x; 1.0725x over previous
//
#include <hip/hip_runtime.h>
#include <hip/hip_bf16.h>
#include <stdint.h>

// Problem constants (from reference): B=1, S=2048, H=1024, I=512, E=16, K=4
#define HH 1024
#define II 512
#define EE 16
#define TT 2048
#define KTOP 4
#define PP (TT * KTOP)      // 8192 routed pairs
#define MAXROWS 12288       // padded row capacity (<= 8192 + 16*127 = 10224 used)

typedef unsigned short u16;
typedef unsigned int u32;
typedef __attribute__((ext_vector_type(8))) short short8;       // bf16 MFMA A/B frag (4 VGPR)
typedef __attribute__((ext_vector_type(4))) float f32x4;        // MFMA C/D frag
typedef __attribute__((ext_vector_type(4))) unsigned short u16x4;
typedef __attribute__((ext_vector_type(4))) unsigned int u32x4;

__device__ __forceinline__ u16 f2bf(float f) {  // fp32 -> bf16 RNE
  union { float f; unsigned u; } v; v.f = f;
  unsigned r = v.u + 0x7fffu + ((v.u >> 16) & 1u);
  return (u16)(r >> 16);
}
__device__ __forceinline__ float bf2f(u16 b) {
  union { unsigned u; float f; } v; v.u = ((unsigned)b) << 16; return v.f;
}

// Direct global->LDS DMA, 16B per lane. LDS dest must be wave-uniform base;
// HW scatters lane l to base + l*16. Swizzle goes on the per-lane global src.
__device__ __forceinline__ void gld16(const u16* g, u16* l) {
  __builtin_amdgcn_global_load_lds(
      (const __attribute__((address_space(1))) unsigned int*)g,
      (__attribute__((address_space(3))) unsigned int*)l, 16, 0, 0);
}

// ---------------- prep: x fp32 -> bf16 ----------------
__global__ void cvt_x_kernel(const float* __restrict__ x, u16* __restrict__ xb) {
  const int i = (blockIdx.x * 256 + threadIdx.x) * 4;
  f32x4 v = *(const f32x4*)(x + i);
  u16x4 o = { f2bf(v[0]), f2bf(v[1]), f2bf(v[2]), f2bf(v[3]) };
  *(u16x4*)(xb + i) = o;
}

// ---------------- prep: all 3 weights, [R][C] fp32 -> [C][R] bf16 per expert ----------------
// Pair-packed dword transpose: u32 = (bf16(src[2rp][c]), bf16(src[2rp+1][c])).
// t32[64 cols][33 rowpairs] (+1 pad): writes ds_write_b32 2-way (free), reads
// ds_read_b128 conflict-free; both global sides 16B-coalesced.
__global__ __launch_bounds__(256) void prep_weights(
    const float* __restrict__ wg, const float* __restrict__ wu, const float* __restrict__ wd,
    u16* __restrict__ WgT, u16* __restrict__ WuT, u16* __restrict__ WdT) {
  __shared__ u32 t32[64][33];
  const int bid = blockIdx.x;
  const int matsel = bid >> 11;
  const int within = bid & 2047;
  const float* src; u16* dst; int R, C, xi, yi;
  if (matsel == 0)      { src = wg; dst = WgT; R = HH; C = II; xi = within & 7;  yi = (within >> 3) & 15; }
  else if (matsel == 1) { src = wu; dst = WuT; R = HH; C = II; xi = within & 7;  yi = (within >> 3) & 15; }
  else                  { src = wd; dst = WdT; R = II; C = HH; xi = within & 15; yi = (within >> 4) & 7;  }
  const int zz = within >> 7;
  const size_t mat = (size_t)zz * R * C;
  const int r0 = yi * 64, c0 = xi * 64;
  const int tid = threadIdx.x;

  // write phase: thread (cq = col-group of 8, rp = rowpair 0..31)
  const int cq = tid & 7, rp = tid >> 3;
  const float* sp = src + mat + (size_t)(r0 + 2 * rp) * C + c0 + cq * 8;
  f32x4 a0 = *(const f32x4*)(sp);
  f32x4 a1 = *(const f32x4*)(sp + 4);
  f32x4 b0 = *(const f32x4*)(sp + C);
  f32x4 b1 = *(const f32x4*)(sp + C + 4);
#pragma unroll
  for (int j = 0; j < 4; j++)
    t32[cq * 8 + j][rp] = (u32)f2bf(a0[j]) | ((u32)f2bf(b0[j]) << 16);
#pragma unroll
  for (int j = 0; j < 4; j++)
    t32[cq * 8 + 4 + j][rp] = (u32)f2bf(a1[j]) | ((u32)f2bf(b1[j]) << 16);
  __syncthreads();

  // read phase: thread (c = out row 0..63, q = quarter)
  const int c = tid >> 2, q = tid & 3;
  u32x4 v0, v1;
#pragma unroll
  for (int j = 0; j < 4; j++) v0[j] = t32[c][q * 8 + j];
#pragma unroll
  for (int j = 0; j < 4; j++) v1[j] = t32[c][q * 8 + 4 + j];
  u16* dp = dst + mat + (size_t)(c0 + c) * R + r0 + q * 16;
  *(u32x4*)(dp) = v0;
  *(u32x4*)(dp + 8) = v1;
}

// ---------------- routing: hierarchical deterministic compaction ----------------
__global__ __launch_bounds__(1024) void route_kernel(
    const int* __restrict__ tidx, const float* __restrict__ tw,
    int* __restrict__ perm, float* __restrict__ wt, int* __restrict__ rowof,
    int* __restrict__ tile_e, int* __restrict__ tile_r,
    int* __restrict__ ntiles) {
  __shared__ int s_e[PP];          // bits0-3: e, bit4: valid, bits16+: in-segment rank
  __shared__ int whist[16][16];
  __shared__ int wbase[16][16];
  __shared__ int pad_lo[EE], pad_hi[EE];

  const int tid = threadIdx.x;
  const int lane = tid & 63;
  const int wv = tid >> 6;

#pragma unroll
  for (int i = 0; i < 2; i++) {
    const int t = tid + i * 1024;
    const int4 v = ((const int4*)tidx)[t];
    const bool v0 = (v.x != v.y) && (v.x != v.z) && (v.x != v.w);
    const bool v1 = (v.y != v.z) && (v.y != v.w);
    const bool v2 = (v.z != v.w);
    s_e[t * 4 + 0] = v.x | (v0 ? 16 : 0);
    s_e[t * 4 + 1] = v.y | (v1 ? 16 : 0);
    s_e[t * 4 + 2] = v.z | (v2 ? 16 : 0);
    s_e[t * 4 + 3] = v.w | 16;
  }
  __syncthreads();

  int h0, h1, h2, h3, h4, h5, h6, h7, h8, h9, h10, h11, h12, h13, h14, h15;
  h0=h1=h2=h3=h4=h5=h6=h7=h8=h9=h10=h11=h12=h13=h14=h15=0;
  const unsigned long long ltm = (1ull << lane) - 1ull;
  for (int c = 0; c < 8; c++) {
    const int p = (wv << 9) + (c << 6) + lane;
    const int se = s_e[p];
    const int e = se & 15;
    const bool valid = (se & 16) != 0;
    int rank = 0;
#define RANK_STEP(J, HJ)                                            \
    {                                                               \
      unsigned long long m = __ballot(valid && (e == J));           \
      if (valid && (e == J)) rank = HJ + __popcll(m & ltm);         \
      HJ += __popcll(m);                                            \
    }
    RANK_STEP(0, h0)  RANK_STEP(1, h1)  RANK_STEP(2, h2)  RANK_STEP(3, h3)
    RANK_STEP(4, h4)  RANK_STEP(5, h5)  RANK_STEP(6, h6)  RANK_STEP(7, h7)
    RANK_STEP(8, h8)  RANK_STEP(9, h9)  RANK_STEP(10, h10) RANK_STEP(11, h11)
    RANK_STEP(12, h12) RANK_STEP(13, h13) RANK_STEP(14, h14) RANK_STEP(15, h15)
#undef RANK_STEP
    if (valid) s_e[p] = se | (rank << 16);
  }
  if (lane == 0) {
    whist[wv][0] = h0;   whist[wv][1] = h1;   whist[wv][2] = h2;   whist[wv][3] = h3;
    whist[wv][4] = h4;   whist[wv][5] = h5;   whist[wv][6] = h6;   whist[wv][7] = h7;
    whist[wv][8] = h8;   whist[wv][9] = h9;   whist[wv][10] = h10; whist[wv][11] = h11;
    whist[wv][12] = h12; whist[wv][13] = h13; whist[wv][14] = h14; whist[wv][15] = h15;
  }
  __syncthreads();

  if (tid == 0) {
    int off = 0, nt = 0;
    for (int j = 0; j < EE; j++) {
      int tot = 0;
      for (int w = 0; w < 16; w++) { wbase[w][j] = off + tot; tot += whist[w][j]; }
      const int cap = (tot + 127) & ~127;
      pad_lo[j] = off + tot;
      pad_hi[j] = off + cap;
      for (int m0 = 0; m0 < cap; m0 += 128) { tile_e[nt] = j; tile_r[nt] = off + m0; nt++; }
      off += cap;
    }
    *ntiles = nt;
  }
  __syncthreads();

#pragma unroll
  for (int i = 0; i < 8; i++) {
    const int p = i * 1024 + tid;
    const int se = s_e[p];
    int pos = -1;
    if (se & 16) {
      const int e = se & 15;
      const int r = se >> 16;
      pos = wbase[p >> 9][e] + r;
      perm[pos] = p >> 2;
      wt[pos] = tw[p];
    }
    rowof[p] = pos;
  }
  for (int j = 0; j < EE; j++) {
    const int lo = pad_lo[j], hi = pad_hi[j];
    for (int i = lo + tid; i < hi; i += 1024) {
      perm[i] = 0;          // pad: token 0 with weight 0 contributes exactly nothing
      wt[i] = 0.f;
    }
  }
}

// ---------------- GEMM1: ACT[r][i] = silu(x@Wg) * (x@Wu) * gate_weight ----------------
// Tile 128(M) x 64(N), BK=64, 4 waves as 2x2. gld16 staging, linear LDS dest,
// swizzle on global source: slot cs = lane&7 holds chunk cs ^ (row&7), row&7 = lane>>3.
__global__ __launch_bounds__(256) void gemm1_kernel(
    const u16* __restrict__ xb, const u16* __restrict__ WgT, const u16* __restrict__ WuT,
    const int* __restrict__ perm, const float* __restrict__ wt,
    const int* __restrict__ tile_e, const int* __restrict__ tile_r,
    const int* __restrict__ ntiles, u16* __restrict__ ACT) {
  const int tileid = blockIdx.y;
  if (tileid >= *ntiles) return;
  const int e = tile_e[tileid];
  const int row0 = tile_r[tileid];
  const int n0 = blockIdx.x * 64;

  __shared__ __align__(16) u16 As[128 * 64];   // 16 KB
  __shared__ __align__(16) u16 Gs[64 * 64];    // 8 KB
  __shared__ __align__(16) u16 Us[64 * 64];    // 8 KB

  const int tid = threadIdx.x;
  const int lane = tid & 63;
  const int wid = tid >> 6;
  const int wm = wid >> 1, wn = wid & 1;
  const int fr = lane & 15, fq = lane >> 4;

  const int lrow = lane >> 3;            // 0..7: row within 8-row group
  const int sc8 = ((lane & 7) ^ lrow) * 8;  // pre-swizzled global chunk (u16 units)

  const u16* gA[4]; u16* lA[4];
#pragma unroll
  for (int j = 0; j < 4; j++) {
    const int trow = j * 32 + wid * 8 + lrow;
    gA[j] = xb + (size_t)perm[row0 + trow] * HH + sc8;
    lA[j] = As + (j * 4 + wid) * 512;
  }
  const u16 *gG[2], *gU[2];
  u16 *lG[2], *lU[2];
#pragma unroll
  for (int j = 0; j < 2; j++) {
    const int nrow = j * 32 + wid * 8 + lrow;
    gG[j] = WgT + ((size_t)e * II + n0 + nrow) * HH + sc8;
    gU[j] = WuT + ((size_t)e * II + n0 + nrow) * HH + sc8;
    lG[j] = Gs + (j * 4 + wid) * 512;
    lU[j] = Us + (j * 4 + wid) * 512;
  }

  f32x4 accg[4][2], accu[4][2];
  const f32x4 vz = {0.f, 0.f, 0.f, 0.f};
#pragma unroll
  for (int m = 0; m < 4; m++)
#pragma unroll
    for (int n = 0; n < 2; n++) { accg[m][n] = vz; accu[m][n] = vz; }

  for (int k0 = 0; k0 < HH; k0 += 64) {
    __syncthreads();
#pragma unroll
    for (int j = 0; j < 4; j++) gld16(gA[j] + k0, lA[j]);
#pragma unroll
    for (int j = 0; j < 2; j++) { gld16(gG[j] + k0, lG[j]); gld16(gU[j] + k0, lU[j]); }
    __syncthreads();

#pragma unroll
    for (int ks = 0; ks < 2; ks++) {
      short8 af[4], bg[2], bu[2];
#pragma unroll
      for (int m = 0; m < 4; m++) {
        const int r = wm * 64 + m * 16 + fr;
        af[m] = *(const short8*)(&As[r * 64 + (((ks * 4 + fq) ^ (r & 7)) * 8)]);
      }
#pragma unroll
      for (int n = 0; n < 2; n++) {
        const int r = wn * 32 + n * 16 + fr;
        bg[n] = *(const short8*)(&Gs[r * 64 + (((ks * 4 + fq) ^ (r & 7)) * 8)]);
        bu[n] = *(const short8*)(&Us[r * 64 + (((ks * 4 + fq) ^ (r & 7)) * 8)]);
      }
#pragma unroll
      for (int m = 0; m < 4; m++)
#pragma unroll
        for (int n = 0; n < 2; n++) {
          accg[m][n] = __builtin_amdgcn_mfma_f32_16x16x32_bf16(af[m], bg[n], accg[m][n], 0, 0, 0);
          accu[m][n] = __builtin_amdgcn_mfma_f32_16x16x32_bf16(af[m], bu[n], accu[m][n], 0, 0, 0);
        }
    }
  }

  // C/D layout: col = lane&15, row = (lane>>4)*4 + j
#pragma unroll
  for (int m = 0; m < 4; m++) {
    const int rbase = wm * 64 + m * 16 + fq * 4;
#pragma unroll
    for (int j = 0; j < 4; j++) {
      const int rloc = rbase + j;
      const float w = wt[row0 + rloc];
#pragma unroll
      for (int n = 0; n < 2; n++) {
        const float g = accg[m][n][j];
        const float u = accu[m][n][j];
        const float s = g / (1.f + __expf(-g));   // silu
        ACT[(size_t)(row0 + rloc) * II + n0 + (wn * 32 + n * 16 + fr)] = f2bf(s * u * w);
      }
    }
  }
}

// ---------------- GEMM2: D[row][h] = ACT @ Wd  (bf16 staging, plain stores) ----------------
// Tile 128(M) x 128(N), BK=64, 4 waves as 2x2; gld16 staging, same swizzle.
__global__ __launch_bounds__(256) void gemm2_kernel(
    const u16* __restrict__ ACT, const u16* __restrict__ WdT,
    const int* __restrict__ tile_e, const int* __restrict__ tile_r,
    const int* __restrict__ ntiles, u16* __restrict__ D) {
  const int tileid = blockIdx.y;
  if (tileid >= *ntiles) return;
  const int e = tile_e[tileid];
  const int row0 = tile_r[tileid];
  const int n0 = blockIdx.x * 128;

  __shared__ __align__(16) u16 As[128 * 64];   // 16 KB
  __shared__ __align__(16) u16 Bs[128 * 64];   // 16 KB

  const int tid = threadIdx.x;
  const int lane = tid & 63;
  const int wid = tid >> 6;
  const int wm = wid >> 1, wn = wid & 1;
  const int fr = lane & 15, fq = lane >> 4;

  const int lrow = lane >> 3;
  const int sc8 = ((lane & 7) ^ lrow) * 8;

  const u16 *gA[4], *gB[4];
  u16 *lA[4], *lB[4];
#pragma unroll
  for (int j = 0; j < 4; j++) {
    const int trow = j * 32 + wid * 8 + lrow;
    gA[j] = ACT + (size_t)(row0 + trow) * II + sc8;
    gB[j] = WdT + ((size_t)e * HH + n0 + trow) * II + sc8;
    lA[j] = As + (j * 4 + wid) * 512;
    lB[j] = Bs + (j * 4 + wid) * 512;
  }

  f32x4 acc[4][4];
  const f32x4 vz = {0.f, 0.f, 0.f, 0.f};
#pragma unroll
  for (int m = 0; m < 4; m++)
#pragma unroll
    for (int n = 0; n < 4; n++) acc[m][n] = vz;

  for (int k0 = 0; k0 < II; k0 += 64) {
    __syncthreads();
#pragma unroll
    for (int j = 0; j < 4; j++) { gld16(gA[j] + k0, lA[j]); gld16(gB[j] + k0, lB[j]); }
    __syncthreads();

#pragma unroll
    for (int ks = 0; ks < 2; ks++) {
      short8 af[4], bf[4];
#pragma unroll
      for (int m = 0; m < 4; m++) {
        const int r = wm * 64 + m * 16 + fr;
        af[m] = *(const short8*)(&As[r * 64 + (((ks * 4 + fq) ^ (r & 7)) * 8)]);
      }
#pragma unroll
      for (int n = 0; n < 4; n++) {
        const int r = wn * 64 + n * 16 + fr;
        bf[n] = *(const short8*)(&Bs[r * 64 + (((ks * 4 + fq) ^ (r & 7)) * 8)]);
      }
#pragma unroll
      for (int m = 0; m < 4; m++)
#pragma unroll
        for (int n = 0; n < 4; n++)
          acc[m][n] = __builtin_amdgcn_mfma_f32_16x16x32_bf16(af[m], bf[n], acc[m][n], 0, 0, 0);
    }
  }

#pragma unroll
  for (int m = 0; m < 4; m++) {
    const int rbase = wm * 64 + m * 16 + fq * 4;
#pragma unroll
    for (int j = 0; j < 4; j++) {
      u16* dp = D + (size_t)(row0 + rbase + j) * HH + n0 + wn * 64 + fr;
#pragma unroll
      for (int n = 0; n < 4; n++)
        dp[n * 16] = f2bf(acc[m][n][j]);
    }
  }
}

// ---------------- combine: out[t][h] = sum over t's valid pairs of D[row][h] ----------------
__global__ __launch_bounds__(256) void combine_kernel(
    const u16* __restrict__ D, const int* __restrict__ rowof,
    float* __restrict__ out) {
  const int t = blockIdx.x;
  const int h = threadIdx.x * 4;
  const int4 r4 = ((const int4*)rowof)[t];
  float a0 = 0.f, a1 = 0.f, a2 = 0.f, a3 = 0.f;
#define ACCUM(R)                                                     \
  if ((R) >= 0) {                                                    \
    u16x4 d = *(const u16x4*)(D + (size_t)(R) * HH + h);             \
    a0 += bf2f(d[0]); a1 += bf2f(d[1]); a2 += bf2f(d[2]); a3 += bf2f(d[3]); \
  }
  ACCUM(r4.x) ACCUM(r4.y) ACCUM(r4.z) ACCUM(r4.w)
#undef ACCUM
  float4 o = { a0, a1, a2, a3 };
  *(float4*)(out + (size_t)t * HH + h) = o;
}

// ---------------- launch ----------------
extern "C" void kernel_launch(void* const* d_in, const int* in_sizes, int n_in,
                              void* d_out, int out_size, void* d_ws, size_t ws_size,
                              hipStream_t stream) {
  const float* x = (const float*)d_in[0];
  const int* tidx = (const int*)d_in[1];
  const float* tw = (const float*)d_in[2];
  const float* wg = (const float*)d_in[3];
  const float* wu = (const float*)d_in[4];
  const float* wd = (const float*)d_in[5];
  float* out = (float*)d_out;

  // ws layout (bytes); total ~67 MB. D overlays WgT/WuT (dead after gemm1).
  char* ws = (char*)d_ws;
  int* ntiles = (int*)(ws + 0);
  int* tile_e = (int*)(ws + 1024);
  int* tile_r = (int*)(ws + 2048);
  int* perm = (int*)(ws + 4096);                 // 12288 ints -> ends 53248
  float* wt = (float*)(ws + 53248);              // 12288 floats -> ends 102400
  int* rowof = (int*)(ws + 102400);              // 8192 ints -> ends 135168
  u16* xb = (u16*)(ws + 262144);                 // [2048][1024] bf16, 4 MB
  u16* WgT = (u16*)(ws + 4456448);               // [E][I][H] bf16, 16.78 MB
  u16* WuT = (u16*)(ws + 21233664);              // [E][I][H] bf16, 16.78 MB
  u16* WdT = (u16*)(ws + 38010880);              // [E][H][I] bf16, 16.78 MB
  u16* ACT = (u16*)(ws + 54788096);              // [MAXROWS][I] bf16, 12.58 MB
  u16* D = (u16*)(ws + 4456448);                 // [MAXROWS][H] bf16, 25.2 MB (overlay)

  cvt_x_kernel<<<TT * HH / 1024, 256, 0, stream>>>(x, xb);
  prep_weights<<<6144, 256, 0, stream>>>(wg, wu, wd, WgT, WuT, WdT);
  route_kernel<<<1, 1024, 0, stream>>>(tidx, tw, perm, wt, rowof, tile_e, tile_r, ntiles);
  gemm1_kernel<<<dim3(II / 64, 80), 256, 0, stream>>>(xb, WgT, WuT, perm, wt,
                                                      tile_e, tile_r, ntiles, ACT);
  gemm2_kernel<<<dim3(HH / 128, 80), 256, 0, stream>>>(ACT, WdT,
                                                       tile_e, tile_r, ntiles, D);
  combine_kernel<<<TT, 256, 0, stream>>>(D, rowof, out);
}

// Round 6
// 96.057 us; speedup vs baseline: 3.7423x; 1.0669x over previous
//
#include <hip/hip_runtime.h>
#include <hip/hip_bf16.h>
#include <stdint.h>

// Problem constants (from reference): B=1, S=2048, H=1024, I=512, E=16, K=4
#define HH 1024
#define II 512
#define EE 16
#define TT 2048
#define KTOP 4
#define PP (TT * KTOP)      // 8192 routed pairs
#define MAXROWS 12288       // padded row capacity (<= 8192 + 16*127 = 10224 used)

typedef unsigned short u16;
typedef unsigned int u32;
typedef __attribute__((ext_vector_type(8))) short short8;       // bf16 MFMA A/B frag (4 VGPR)
typedef __attribute__((ext_vector_type(4))) float f32x4;        // MFMA C/D frag
typedef __attribute__((ext_vector_type(4))) unsigned short u16x4;
typedef __attribute__((ext_vector_type(8))) unsigned short u16x8;
typedef __attribute__((ext_vector_type(4))) unsigned int u32x4;

__device__ __forceinline__ u16 f2bf(float f) {  // fp32 -> bf16 RNE
  union { float f; unsigned u; } v; v.f = f;
  unsigned r = v.u + 0x7fffu + ((v.u >> 16) & 1u);
  return (u16)(r >> 16);
}
__device__ __forceinline__ float bf2f(u16 b) {
  union { unsigned u; float f; } v; v.u = ((unsigned)b) << 16; return v.f;
}

// Direct global->LDS DMA, 16B per lane. LDS dest must be wave-uniform base;
// HW scatters lane l to base + l*16. Swizzle goes on the per-lane global src.
__device__ __forceinline__ void gld16(const u16* g, u16* l) {
  __builtin_amdgcn_global_load_lds(
      (const __attribute__((address_space(1))) unsigned int*)g,
      (__attribute__((address_space(3))) unsigned int*)l, 16, 0, 0);
}

// ================= merged prep stage =================
// block 0            : routing (4 waves, ballot-rank compaction)
// blocks 1..512      : x fp32 -> bf16 convert (16 elems/thread)
// blocks 513..6656   : weight transpose+convert, 128x64 source tile per block,
//                      pair-packed dword transpose, pipelined two halves.
// Route block is FIRST in dispatch order so it starts at t=0 and its ~10us of
// wave-serial ballots hide under the transpose blocks' memory time.
union PLds {
  u16 s_e[PP];          // 16 KB: routing state  [4:0]=e|valid<<4, [15:5]=rank
  u32 t32[64][33];      // 8.4 KB: transpose tile (pair-packed dwords)
};

__global__ __launch_bounds__(256) void prep_stage(
    const float* __restrict__ x, const int* __restrict__ tidx,
    const float* __restrict__ tw,
    const float* __restrict__ wg, const float* __restrict__ wu,
    const float* __restrict__ wd,
    u16* __restrict__ xb, u16* __restrict__ WgT, u16* __restrict__ WuT,
    u16* __restrict__ WdT,
    int* __restrict__ perm, float* __restrict__ wt, int* __restrict__ rowof,
    int* __restrict__ tile_e, int* __restrict__ tile_r,
    int* __restrict__ ntiles) {
  __shared__ PLds L;
  __shared__ int whist[4][16], wbase[4][16];
  __shared__ int pad_lo[EE], pad_hi[EE];

  const int bid = blockIdx.x;
  const int tid = threadIdx.x;

  if (bid == 0) {
    // ---------------- routing ----------------
    const int lane = tid & 63;
    const int wv = tid >> 6;        // 0..3, owns pairs [wv*2048, wv*2048+2048)

    // Phase 1: load topk_idx (int4/token), last-dup-wins validity, pack to LDS
#pragma unroll
    for (int i = 0; i < 8; i++) {
      const int t = i * 256 + tid;
      const int4 v = ((const int4*)tidx)[t];
      const bool v0 = (v.x != v.y) && (v.x != v.z) && (v.x != v.w);
      const bool v1 = (v.y != v.z) && (v.y != v.w);
      const bool v2 = (v.z != v.w);
      L.s_e[t * 4 + 0] = (u16)(v.x | (v0 ? 16 : 0));
      L.s_e[t * 4 + 1] = (u16)(v.y | (v1 ? 16 : 0));
      L.s_e[t * 4 + 2] = (u16)(v.z | (v2 ? 16 : 0));
      L.s_e[t * 4 + 3] = (u16)(v.w | 16);
    }
    __syncthreads();

    // Phase 2: per-wave in-order ranking of its 2048-pair segment group
    int h0, h1, h2, h3, h4, h5, h6, h7, h8, h9, h10, h11, h12, h13, h14, h15;
    h0=h1=h2=h3=h4=h5=h6=h7=h8=h9=h10=h11=h12=h13=h14=h15=0;
    const unsigned long long ltm = (1ull << lane) - 1ull;
    for (int c = 0; c < 32; c++) {
      const int p = (wv << 11) + (c << 6) + lane;
      const u16 se = L.s_e[p];
      const int e = se & 15;
      const bool valid = (se & 16) != 0;
      int rank = 0;
#define RANK_STEP(J, HJ)                                            \
      {                                                             \
        unsigned long long m = __ballot(valid && (e == J));         \
        if (valid && (e == J)) rank = HJ + __popcll(m & ltm);       \
        HJ += __popcll(m);                                          \
      }
      RANK_STEP(0, h0)  RANK_STEP(1, h1)  RANK_STEP(2, h2)  RANK_STEP(3, h3)
      RANK_STEP(4, h4)  RANK_STEP(5, h5)  RANK_STEP(6, h6)  RANK_STEP(7, h7)
      RANK_STEP(8, h8)  RANK_STEP(9, h9)  RANK_STEP(10, h10) RANK_STEP(11, h11)
      RANK_STEP(12, h12) RANK_STEP(13, h13) RANK_STEP(14, h14) RANK_STEP(15, h15)
#undef RANK_STEP
      if (valid) L.s_e[p] = (u16)(se | (rank << 5));   // rank < 2048, 11 bits
    }
    if (lane == 0) {
      whist[wv][0] = h0;   whist[wv][1] = h1;   whist[wv][2] = h2;   whist[wv][3] = h3;
      whist[wv][4] = h4;   whist[wv][5] = h5;   whist[wv][6] = h6;   whist[wv][7] = h7;
      whist[wv][8] = h8;   whist[wv][9] = h9;   whist[wv][10] = h10; whist[wv][11] = h11;
      whist[wv][12] = h12; whist[wv][13] = h13; whist[wv][14] = h14; whist[wv][15] = h15;
    }
    __syncthreads();

    // Phase 3: tiny scan -> bases, tile table, pad ranges
    if (tid == 0) {
      int off = 0, nt = 0;
      for (int j = 0; j < EE; j++) {
        int tot = 0;
        for (int w = 0; w < 4; w++) { wbase[w][j] = off + tot; tot += whist[w][j]; }
        const int cap = (tot + 127) & ~127;
        pad_lo[j] = off + tot;
        pad_hi[j] = off + cap;
        for (int m0 = 0; m0 < cap; m0 += 128) { tile_e[nt] = j; tile_r[nt] = off + m0; nt++; }
        off += cap;
      }
      *ntiles = nt;
    }
    __syncthreads();

    // Phase 4: scatter perm/wt/rowof, then pad fill
#pragma unroll
    for (int i = 0; i < 32; i++) {
      const int p = i * 256 + tid;
      const u16 se = L.s_e[p];
      int pos = -1;
      if (se & 16) {
        const int e = se & 15;
        const int r = se >> 5;
        pos = wbase[p >> 11][e] + r;
        perm[pos] = p >> 2;
        wt[pos] = tw[p];
      }
      rowof[p] = pos;
    }
    for (int j = 0; j < EE; j++) {
      const int lo = pad_lo[j], hi = pad_hi[j];
      for (int i = lo + tid; i < hi; i += 256) {
        perm[i] = 0;        // pad: token 0 with weight 0 contributes exactly nothing
        wt[i] = 0.f;
      }
    }
    return;
  }

  if (bid <= 512) {
    // ---------------- x fp32 -> bf16 (16 elems/thread) ----------------
    const int base = ((bid - 1) * 256 + tid) * 16;
    f32x4 v0 = *(const f32x4*)(x + base);
    f32x4 v1 = *(const f32x4*)(x + base + 4);
    f32x4 v2 = *(const f32x4*)(x + base + 8);
    f32x4 v3 = *(const f32x4*)(x + base + 12);
    u16x8 o0 = { f2bf(v0[0]), f2bf(v0[1]), f2bf(v0[2]), f2bf(v0[3]),
                 f2bf(v1[0]), f2bf(v1[1]), f2bf(v1[2]), f2bf(v1[3]) };
    u16x8 o1 = { f2bf(v2[0]), f2bf(v2[1]), f2bf(v2[2]), f2bf(v2[3]),
                 f2bf(v3[0]), f2bf(v3[1]), f2bf(v3[2]), f2bf(v3[3]) };
    *(u16x8*)(xb + base) = o0;
    *(u16x8*)(xb + base + 8) = o1;
    return;
  }

  // ---------------- weight transpose+convert, 128x64 source tile ----------------
  const int pb = bid - 513;           // 0..3071
  const int matsel = pb >> 10;
  const int within = pb & 1023;
  const int zz = within >> 6;
  const int sub = within & 63;
  const float* src; u16* dst; int R, C, xi, yi;
  if (matsel == 0)      { src = wg; dst = WgT; R = HH; C = II; xi = sub & 7;  yi = sub >> 3; }
  else if (matsel == 1) { src = wu; dst = WuT; R = HH; C = II; xi = sub & 7;  yi = sub >> 3; }
  else                  { src = wd; dst = WdT; R = II; C = HH; xi = sub & 15; yi = sub >> 4; }
  const size_t mat = (size_t)zz * R * C;
  const int r0 = yi * 128, c0 = xi * 64;

  // issue all 8 loads up front (both halves) for ILP
  const int cq = tid & 7, rp = tid >> 3;          // col-group, rowpair 0..31
  const float* sp0 = src + mat + (size_t)(r0 + 2 * rp) * C + c0 + cq * 8;
  const float* sp1 = sp0 + (size_t)64 * C;
  const f32x4 a0 = *(const f32x4*)(sp0);
  const f32x4 a1 = *(const f32x4*)(sp0 + 4);
  const f32x4 b0 = *(const f32x4*)(sp0 + C);
  const f32x4 b1 = *(const f32x4*)(sp0 + C + 4);
  const f32x4 e0 = *(const f32x4*)(sp1);
  const f32x4 e1 = *(const f32x4*)(sp1 + 4);
  const f32x4 g0 = *(const f32x4*)(sp1 + C);
  const f32x4 g1 = *(const f32x4*)(sp1 + C + 4);

  const int c = tid >> 2, q = tid & 3;            // read-phase coords
  u16* dp = dst + mat + (size_t)(c0 + c) * R + r0 + q * 16;

  // half 0
#pragma unroll
  for (int j = 0; j < 4; j++)
    L.t32[cq * 8 + j][rp] = (u32)f2bf(a0[j]) | ((u32)f2bf(b0[j]) << 16);
#pragma unroll
  for (int j = 0; j < 4; j++)
    L.t32[cq * 8 + 4 + j][rp] = (u32)f2bf(a1[j]) | ((u32)f2bf(b1[j]) << 16);
  __syncthreads();
  {
    u32x4 v0, v1;
#pragma unroll
    for (int j = 0; j < 4; j++) v0[j] = L.t32[c][q * 8 + j];
#pragma unroll
    for (int j = 0; j < 4; j++) v1[j] = L.t32[c][q * 8 + 4 + j];
    *(u32x4*)(dp) = v0;
    *(u32x4*)(dp + 8) = v1;
  }
  __syncthreads();
  // half 1 (source rows r0+64..r0+127 -> output cols +64)
#pragma unroll
  for (int j = 0; j < 4; j++)
    L.t32[cq * 8 + j][rp] = (u32)f2bf(e0[j]) | ((u32)f2bf(g0[j]) << 16);
#pragma unroll
  for (int j = 0; j < 4; j++)
    L.t32[cq * 8 + 4 + j][rp] = (u32)f2bf(e1[j]) | ((u32)f2bf(g1[j]) << 16);
  __syncthreads();
  {
    u32x4 v0, v1;
#pragma unroll
    for (int j = 0; j < 4; j++) v0[j] = L.t32[c][q * 8 + j];
#pragma unroll
    for (int j = 0; j < 4; j++) v1[j] = L.t32[c][q * 8 + 4 + j];
    *(u32x4*)(dp + 64) = v0;
    *(u32x4*)(dp + 72) = v1;
  }
}

// ---------------- GEMM1: ACT[r][i] = silu(x@Wg) * (x@Wu) * gate_weight ----------------
// Tile 128(M) x 64(N), BK=64, 4 waves as 2x2. gld16 staging, linear LDS dest,
// swizzle on global source: slot cs = lane&7 holds chunk cs ^ (row&7), row&7 = lane>>3.
__global__ __launch_bounds__(256) void gemm1_kernel(
    const u16* __restrict__ xb, const u16* __restrict__ WgT, const u16* __restrict__ WuT,
    const int* __restrict__ perm, const float* __restrict__ wt,
    const int* __restrict__ tile_e, const int* __restrict__ tile_r,
    const int* __restrict__ ntiles, u16* __restrict__ ACT) {
  const int tileid = blockIdx.y;
  if (tileid >= *ntiles) return;
  const int e = tile_e[tileid];
  const int row0 = tile_r[tileid];
  const int n0 = blockIdx.x * 64;

  __shared__ __align__(16) u16 As[128 * 64];   // 16 KB
  __shared__ __align__(16) u16 Gs[64 * 64];    // 8 KB
  __shared__ __align__(16) u16 Us[64 * 64];    // 8 KB

  const int tid = threadIdx.x;
  const int lane = tid & 63;
  const int wid = tid >> 6;
  const int wm = wid >> 1, wn = wid & 1;
  const int fr = lane & 15, fq = lane >> 4;

  const int lrow = lane >> 3;            // 0..7: row within 8-row group
  const int sc8 = ((lane & 7) ^ lrow) * 8;  // pre-swizzled global chunk (u16 units)

  const u16* gA[4]; u16* lA[4];
#pragma unroll
  for (int j = 0; j < 4; j++) {
    const int trow = j * 32 + wid * 8 + lrow;
    gA[j] = xb + (size_t)perm[row0 + trow] * HH + sc8;
    lA[j] = As + (j * 4 + wid) * 512;
  }
  const u16 *gG[2], *gU[2];
  u16 *lG[2], *lU[2];
#pragma unroll
  for (int j = 0; j < 2; j++) {
    const int nrow = j * 32 + wid * 8 + lrow;
    gG[j] = WgT + ((size_t)e * II + n0 + nrow) * HH + sc8;
    gU[j] = WuT + ((size_t)e * II + n0 + nrow) * HH + sc8;
    lG[j] = Gs + (j * 4 + wid) * 512;
    lU[j] = Us + (j * 4 + wid) * 512;
  }

  f32x4 accg[4][2], accu[4][2];
  const f32x4 vz = {0.f, 0.f, 0.f, 0.f};
#pragma unroll
  for (int m = 0; m < 4; m++)
#pragma unroll
    for (int n = 0; n < 2; n++) { accg[m][n] = vz; accu[m][n] = vz; }

  for (int k0 = 0; k0 < HH; k0 += 64) {
    __syncthreads();
#pragma unroll
    for (int j = 0; j < 4; j++) gld16(gA[j] + k0, lA[j]);
#pragma unroll
    for (int j = 0; j < 2; j++) { gld16(gG[j] + k0, lG[j]); gld16(gU[j] + k0, lU[j]); }
    __syncthreads();

#pragma unroll
    for (int ks = 0; ks < 2; ks++) {
      short8 af[4], bg[2], bu[2];
#pragma unroll
      for (int m = 0; m < 4; m++) {
        const int r = wm * 64 + m * 16 + fr;
        af[m] = *(const short8*)(&As[r * 64 + (((ks * 4 + fq) ^ (r & 7)) * 8)]);
      }
#pragma unroll
      for (int n = 0; n < 2; n++) {
        const int r = wn * 32 + n * 16 + fr;
        bg[n] = *(const short8*)(&Gs[r * 64 + (((ks * 4 + fq) ^ (r & 7)) * 8)]);
        bu[n] = *(const short8*)(&Us[r * 64 + (((ks * 4 + fq) ^ (r & 7)) * 8)]);
      }
#pragma unroll
      for (int m = 0; m < 4; m++)
#pragma unroll
        for (int n = 0; n < 2; n++) {
          accg[m][n] = __builtin_amdgcn_mfma_f32_16x16x32_bf16(af[m], bg[n], accg[m][n], 0, 0, 0);
          accu[m][n] = __builtin_amdgcn_mfma_f32_16x16x32_bf16(af[m], bu[n], accu[m][n], 0, 0, 0);
        }
    }
  }

  // C/D layout: col = lane&15, row = (lane>>4)*4 + j
#pragma unroll
  for (int m = 0; m < 4; m++) {
    const int rbase = wm * 64 + m * 16 + fq * 4;
#pragma unroll
    for (int j = 0; j < 4; j++) {
      const int rloc = rbase + j;
      const float w = wt[row0 + rloc];
#pragma unroll
      for (int n = 0; n < 2; n++) {
        const float g = accg[m][n][j];
        const float u = accu[m][n][j];
        const float s = g / (1.f + __expf(-g));   // silu
        ACT[(size_t)(row0 + rloc) * II + n0 + (wn * 32 + n * 16 + fr)] = f2bf(s * u * w);
      }
    }
  }
}

// ---------------- GEMM2: D[row][h] = ACT @ Wd  (bf16 staging, plain stores) ----------------
// Tile 128(M) x 128(N), BK=64, 4 waves as 2x2; gld16 staging, same swizzle.
__global__ __launch_bounds__(256) void gemm2_kernel(
    const u16* __restrict__ ACT, const u16* __restrict__ WdT,
    const int* __restrict__ tile_e, const int* __restrict__ tile_r,
    const int* __restrict__ ntiles, u16* __restrict__ D) {
  const int tileid = blockIdx.y;
  if (tileid >= *ntiles) return;
  const int e = tile_e[tileid];
  const int row0 = tile_r[tileid];
  const int n0 = blockIdx.x * 128;

  __shared__ __align__(16) u16 As[128 * 64];   // 16 KB
  __shared__ __align__(16) u16 Bs[128 * 64];   // 16 KB

  const int tid = threadIdx.x;
  const int lane = tid & 63;
  const int wid = tid >> 6;
  const int wm = wid >> 1, wn = wid & 1;
  const int fr = lane & 15, fq = lane >> 4;

  const int lrow = lane >> 3;
  const int sc8 = ((lane & 7) ^ lrow) * 8;

  const u16 *gA[4], *gB[4];
  u16 *lA[4], *lB[4];
#pragma unroll
  for (int j = 0; j < 4; j++) {
    const int trow = j * 32 + wid * 8 + lrow;
    gA[j] = ACT + (size_t)(row0 + trow) * II + sc8;
    gB[j] = WdT + ((size_t)e * HH + n0 + trow) * II + sc8;
    lA[j] = As + (j * 4 + wid) * 512;
    lB[j] = Bs + (j * 4 + wid) * 512;
  }

  f32x4 acc[4][4];
  const f32x4 vz = {0.f, 0.f, 0.f, 0.f};
#pragma unroll
  for (int m = 0; m < 4; m++)
#pragma unroll
    for (int n = 0; n < 4; n++) acc[m][n] = vz;

  for (int k0 = 0; k0 < II; k0 += 64) {
    __syncthreads();
#pragma unroll
    for (int j = 0; j < 4; j++) { gld16(gA[j] + k0, lA[j]); gld16(gB[j] + k0, lB[j]); }
    __syncthreads();

#pragma unroll
    for (int ks = 0; ks < 2; ks++) {
      short8 af[4], bf[4];
#pragma unroll
      for (int m = 0; m < 4; m++) {
        const int r = wm * 64 + m * 16 + fr;
        af[m] = *(const short8*)(&As[r * 64 + (((ks * 4 + fq) ^ (r & 7)) * 8)]);
      }
#pragma unroll
      for (int n = 0; n < 4; n++) {
        const int r = wn * 64 + n * 16 + fr;
        bf[n] = *(const short8*)(&Bs[r * 64 + (((ks * 4 + fq) ^ (r & 7)) * 8)]);
      }
#pragma unroll
      for (int m = 0; m < 4; m++)
#pragma unroll
        for (int n = 0; n < 4; n++)
          acc[m][n] = __builtin_amdgcn_mfma_f32_16x16x32_bf16(af[m], bf[n], acc[m][n], 0, 0, 0);
    }
  }

#pragma unroll
  for (int m = 0; m < 4; m++) {
    const int rbase = wm * 64 + m * 16 + fq * 4;
#pragma unroll
    for (int j = 0; j < 4; j++) {
      u16* dp = D + (size_t)(row0 + rbase + j) * HH + n0 + wn * 64 + fr;
#pragma unroll
      for (int n = 0; n < 4; n++)
        dp[n * 16] = f2bf(acc[m][n][j]);
    }
  }
}

// ---------------- combine: out[t][h] = sum over t's valid pairs of D[row][h] ----------------
__global__ __launch_bounds__(256) void combine_kernel(
    const u16* __restrict__ D, const int* __restrict__ rowof,
    float* __restrict__ out) {
  const int t = blockIdx.x;
  const int h = threadIdx.x * 4;
  const int4 r4 = ((const int4*)rowof)[t];
  float a0 = 0.f, a1 = 0.f, a2 = 0.f, a3 = 0.f;
#define ACCUM(R)                                                     \
  if ((R) >= 0) {                                                    \
    u16x4 d = *(const u16x4*)(D + (size_t)(R) * HH + h);             \
    a0 += bf2f(d[0]); a1 += bf2f(d[1]); a2 += bf2f(d[2]); a3 += bf2f(d[3]); \
  }
  ACCUM(r4.x) ACCUM(r4.y) ACCUM(r4.z) ACCUM(r4.w)
#undef ACCUM
  float4 o = { a0, a1, a2, a3 };
  *(float4*)(out + (size_t)t * HH + h) = o;
}

// ---------------- launch ----------------
extern "C" void kernel_launch(void* const* d_in, const int* in_sizes, int n_in,
                              void* d_out, int out_size, void* d_ws, size_t ws_size,
                              hipStream_t stream) {
  const float* x = (const float*)d_in[0];
  const int* tidx = (const int*)d_in[1];
  const float* tw = (const float*)d_in[2];
  const float* wg = (const float*)d_in[3];
  const float* wu = (const float*)d_in[4];
  const float* wd = (const float*)d_in[5];
  float* out = (float*)d_out;

  // ws layout (bytes); total ~67 MB. D overlays WgT/WuT (dead after gemm1).
  char* ws = (char*)d_ws;
  int* ntiles = (int*)(ws + 0);
  int* tile_e = (int*)(ws + 1024);
  int* tile_r = (int*)(ws + 2048);
  int* perm = (int*)(ws + 4096);                 // 12288 ints -> ends 53248
  float* wt = (float*)(ws + 53248);              // 12288 floats -> ends 102400
  int* rowof = (int*)(ws + 102400);              // 8192 ints -> ends 135168
  u16* xb = (u16*)(ws + 262144);                 // [2048][1024] bf16, 4 MB
  u16* WgT = (u16*)(ws + 4456448);               // [E][I][H] bf16, 16.78 MB
  u16* WuT = (u16*)(ws + 21233664);              // [E][I][H] bf16, 16.78 MB
  u16* WdT = (u16*)(ws + 38010880);              // [E][H][I] bf16, 16.78 MB
  u16* ACT = (u16*)(ws + 54788096);              // [MAXROWS][I] bf16, 12.58 MB
  u16* D = (u16*)(ws + 4456448);                 // [MAXROWS][H] bf16, 25.2 MB (overlay)

  prep_stage<<<6657, 256, 0, stream>>>(x, tidx, tw, wg, wu, wd,
                                       xb, WgT, WuT, WdT,
                                       perm, wt, rowof, tile_e, tile_r, ntiles);
  gemm1_kernel<<<dim3(II / 64, 80), 256, 0, stream>>>(xb, WgT, WuT, perm, wt,
                                                      tile_e, tile_r, ntiles, ACT);
  gemm2_kernel<<<dim3(HH / 128, 80), 256, 0, stream>>>(ACT, WdT,
                                                       tile_e, tile_r, ntiles, D);
  combine_kernel<<<TT, 256, 0, stream>>>(D, rowof, out);
}

// Round 7
// 89.610 us; speedup vs baseline: 4.0115x; 1.0719x over previous
//
#include <hip/hip_runtime.h>
#include <hip/hip_bf16.h>
#include <stdint.h>

// Problem constants: B=1, S=2048, H=1024, I=512, E=16, K=4
#define HH 1024
#define II 512
#define EE 16
#define TT 2048
#define KTOP 4
#define PP (TT * KTOP)      // 8192 routed pairs
#define MAXROWS 12288       // padded row capacity

typedef unsigned short u16;
typedef unsigned int u32;
typedef __attribute__((ext_vector_type(8))) short short8;       // bf16 MFMA A/B frag
typedef __attribute__((ext_vector_type(4))) float f32x4;        // MFMA C/D frag
typedef __attribute__((ext_vector_type(4))) unsigned short u16x4;
typedef __attribute__((ext_vector_type(8))) unsigned short u16x8;

__device__ __forceinline__ u16 f2bf(float f) {  // fp32 -> bf16 RNE (manual)
  union { float f; unsigned u; } v; v.f = f;
  unsigned r = v.u + 0x7fffu + ((v.u >> 16) & 1u);
  return (u16)(r >> 16);
}
__device__ __forceinline__ float bf2f(u16 b) {
  union { unsigned u; float f; } v; v.u = ((unsigned)b) << 16; return v.f;
}
__device__ __forceinline__ short f2bf_hw(float f) {  // RNE via HW cvt (compiler fuses pairs)
  __hip_bfloat16 h = __float2bfloat16(f);
  union { __hip_bfloat16 h; short s; } v; v.h = h; return v.s;
}

// Direct global->LDS DMA, 16B per lane; dest wave-uniform base + lane*16.
__device__ __forceinline__ void gld16(const u16* g, u16* l) {
  __builtin_amdgcn_global_load_lds(
      (const __attribute__((address_space(1))) unsigned int*)g,
      (__attribute__((address_space(3))) unsigned int*)l, 16, 0, 0);
}

// ================= prep: route (block 0, 16 waves) + x cvt (blocks 1..128) ==========
__global__ __launch_bounds__(1024) void prep_small(
    const float* __restrict__ x, const int* __restrict__ tidx,
    const float* __restrict__ tw,
    u16* __restrict__ xb,
    int* __restrict__ perm, float* __restrict__ wt, int* __restrict__ rowof,
    int* __restrict__ tile_e, int* __restrict__ tile_r,
    int* __restrict__ ntiles) {
  __shared__ int s_e[PP];          // bits0-3: e, bit4: valid, bits16+: rank
  __shared__ int whist[16][16];
  __shared__ int wbase[16][16];
  __shared__ int pad_lo[EE], pad_hi[EE];

  const int bid = blockIdx.x;
  const int tid = threadIdx.x;

  if (bid == 0) {
    // ---- routing: 16 waves, each ranks a 512-pair segment (proven R2-R5 form) ----
    const int lane = tid & 63;
    const int wv = tid >> 6;

#pragma unroll
    for (int i = 0; i < 2; i++) {
      const int t = tid + i * 1024;
      const int4 v = ((const int4*)tidx)[t];
      const bool v0 = (v.x != v.y) && (v.x != v.z) && (v.x != v.w);
      const bool v1 = (v.y != v.z) && (v.y != v.w);
      const bool v2 = (v.z != v.w);
      s_e[t * 4 + 0] = v.x | (v0 ? 16 : 0);
      s_e[t * 4 + 1] = v.y | (v1 ? 16 : 0);
      s_e[t * 4 + 2] = v.z | (v2 ? 16 : 0);
      s_e[t * 4 + 3] = v.w | 16;
    }
    __syncthreads();

    int h0, h1, h2, h3, h4, h5, h6, h7, h8, h9, h10, h11, h12, h13, h14, h15;
    h0=h1=h2=h3=h4=h5=h6=h7=h8=h9=h10=h11=h12=h13=h14=h15=0;
    const unsigned long long ltm = (1ull << lane) - 1ull;
    for (int c = 0; c < 8; c++) {
      const int p = (wv << 9) + (c << 6) + lane;
      const int se = s_e[p];
      const int e = se & 15;
      const bool valid = (se & 16) != 0;
      int rank = 0;
#define RANK_STEP(J, HJ)                                            \
      {                                                             \
        unsigned long long m = __ballot(valid && (e == J));         \
        if (valid && (e == J)) rank = HJ + __popcll(m & ltm);       \
        HJ += __popcll(m);                                          \
      }
      RANK_STEP(0, h0)  RANK_STEP(1, h1)  RANK_STEP(2, h2)  RANK_STEP(3, h3)
      RANK_STEP(4, h4)  RANK_STEP(5, h5)  RANK_STEP(6, h6)  RANK_STEP(7, h7)
      RANK_STEP(8, h8)  RANK_STEP(9, h9)  RANK_STEP(10, h10) RANK_STEP(11, h11)
      RANK_STEP(12, h12) RANK_STEP(13, h13) RANK_STEP(14, h14) RANK_STEP(15, h15)
#undef RANK_STEP
      if (valid) s_e[p] = se | (rank << 16);
    }
    if (lane == 0) {
      whist[wv][0] = h0;   whist[wv][1] = h1;   whist[wv][2] = h2;   whist[wv][3] = h3;
      whist[wv][4] = h4;   whist[wv][5] = h5;   whist[wv][6] = h6;   whist[wv][7] = h7;
      whist[wv][8] = h8;   whist[wv][9] = h9;   whist[wv][10] = h10; whist[wv][11] = h11;
      whist[wv][12] = h12; whist[wv][13] = h13; whist[wv][14] = h14; whist[wv][15] = h15;
    }
    __syncthreads();

    if (tid == 0) {
      int off = 0, nt = 0;
      for (int j = 0; j < EE; j++) {
        int tot = 0;
        for (int w = 0; w < 16; w++) { wbase[w][j] = off + tot; tot += whist[w][j]; }
        const int cap = (tot + 127) & ~127;
        pad_lo[j] = off + tot;
        pad_hi[j] = off + cap;
        for (int m0 = 0; m0 < cap; m0 += 128) { tile_e[nt] = j; tile_r[nt] = off + m0; nt++; }
        off += cap;
      }
      *ntiles = nt;
    }
    __syncthreads();

#pragma unroll
    for (int i = 0; i < 8; i++) {
      const int p = i * 1024 + tid;
      const int se = s_e[p];
      int pos = -1;
      if (se & 16) {
        const int e = se & 15;
        const int r = se >> 16;
        pos = wbase[p >> 9][e] + r;
        perm[pos] = p >> 2;
        wt[pos] = tw[p];
      }
      rowof[p] = pos;
    }
    for (int j = 0; j < EE; j++) {
      const int lo = pad_lo[j], hi = pad_hi[j];
      for (int i = lo + tid; i < hi; i += 1024) {
        perm[i] = 0;          // pad: token 0 with weight 0 contributes nothing
        wt[i] = 0.f;
      }
    }
    return;
  }

  // ---- x fp32 -> bf16, 16 elems/thread ----
  const int base = ((bid - 1) * 1024 + tid) * 16;
  f32x4 v0 = *(const f32x4*)(x + base);
  f32x4 v1 = *(const f32x4*)(x + base + 4);
  f32x4 v2 = *(const f32x4*)(x + base + 8);
  f32x4 v3 = *(const f32x4*)(x + base + 12);
  u16x8 o0 = { f2bf(v0[0]), f2bf(v0[1]), f2bf(v0[2]), f2bf(v0[3]),
               f2bf(v1[0]), f2bf(v1[1]), f2bf(v1[2]), f2bf(v1[3]) };
  u16x8 o1 = { f2bf(v2[0]), f2bf(v2[1]), f2bf(v2[2]), f2bf(v2[3]),
               f2bf(v3[0]), f2bf(v3[1]), f2bf(v3[2]), f2bf(v3[3]) };
  *(u16x8*)(xb + base) = o0;
  *(u16x8*)(xb + base + 8) = o1;
}

// ---------------- GEMM1: ACT = silu(x@Wg) * (x@Wu) * gate_weight ----------------
// Tile 128(M) x 64(N), BK=64. Wave w owns ALL 128 M x 16 n-cols (n = n0+w*16+fr):
// B-frags load DIRECTLY from k-major fp32 weights (8 strided dwords + HW cvt),
// A via gld16 into XOR-swizzled LDS (unchanged, proven).
__global__ __launch_bounds__(256) void gemm1_kernel(
    const u16* __restrict__ xb, const float* __restrict__ wg,
    const float* __restrict__ wu,
    const int* __restrict__ perm, const float* __restrict__ wt,
    const int* __restrict__ tile_e, const int* __restrict__ tile_r,
    const int* __restrict__ ntiles, u16* __restrict__ ACT) {
  const int tileid = blockIdx.y;
  if (tileid >= *ntiles) return;
  const int e = tile_e[tileid];
  const int row0 = tile_r[tileid];
  const int n0 = blockIdx.x * 64;

  __shared__ __align__(16) u16 As[128 * 64];   // 16 KB

  const int tid = threadIdx.x;
  const int lane = tid & 63;
  const int wid = tid >> 6;
  const int fr = lane & 15, fq = lane >> 4;

  const int lrow = lane >> 3;
  const int sc8 = ((lane & 7) ^ lrow) * 8;     // pre-swizzled source chunk

  const u16* gA[4]; u16* lA[4];
#pragma unroll
  for (int j = 0; j < 4; j++) {
    const int trow = j * 32 + wid * 8 + lrow;
    gA[j] = xb + (size_t)perm[row0 + trow] * HH + sc8;
    lA[j] = As + (j * 4 + wid) * 512;
  }

  const int ncol = n0 + wid * 16 + fr;         // this lane's output column
  const float* gbase = wg + (size_t)e * HH * II + ncol;
  const float* ubase = wu + (size_t)e * HH * II + ncol;

  f32x4 accg[8], accu[8];
  const f32x4 vz = {0.f, 0.f, 0.f, 0.f};
#pragma unroll
  for (int m = 0; m < 8; m++) { accg[m] = vz; accu[m] = vz; }

  for (int k0 = 0; k0 < HH; k0 += 64) {
    // B: lane needs W[k0+ks*32+fq*8+j][ncol] -- strided dwords, issued early
    float fg[2][8], fu[2][8];
#pragma unroll
    for (int ks = 0; ks < 2; ks++)
#pragma unroll
      for (int j = 0; j < 8; j++) {
        const size_t koff = (size_t)(k0 + ks * 32 + fq * 8 + j) * II;
        fg[ks][j] = gbase[koff];
        fu[ks][j] = ubase[koff];
      }
    __syncthreads();                 // prev iter's A reads done
#pragma unroll
    for (int j = 0; j < 4; j++) gld16(gA[j] + k0, lA[j]);
    __syncthreads();                 // A staged (drains vmcnt)

    short8 bg[2], bu[2];
#pragma unroll
    for (int ks = 0; ks < 2; ks++)
#pragma unroll
      for (int j = 0; j < 8; j++) {
        bg[ks][j] = f2bf_hw(fg[ks][j]);
        bu[ks][j] = f2bf_hw(fu[ks][j]);
      }

#pragma unroll
    for (int ks = 0; ks < 2; ks++)
#pragma unroll
      for (int m = 0; m < 8; m++) {
        const int r = m * 16 + fr;
        const short8 a = *(const short8*)(&As[r * 64 + (((ks * 4 + fq) ^ (r & 7)) * 8)]);
        accg[m] = __builtin_amdgcn_mfma_f32_16x16x32_bf16(a, bg[ks], accg[m], 0, 0, 0);
        accu[m] = __builtin_amdgcn_mfma_f32_16x16x32_bf16(a, bu[ks], accu[m], 0, 0, 0);
      }
  }

  // C/D: col = lane&15 (=fr), row = fq*4 + jj within each 16-row m-frag
#pragma unroll
  for (int m = 0; m < 8; m++) {
#pragma unroll
    for (int jj = 0; jj < 4; jj++) {
      const int rloc = m * 16 + fq * 4 + jj;
      const float w = wt[row0 + rloc];
      const float g = accg[m][jj];
      const float u = accu[m][jj];
      const float s = g / (1.f + __expf(-g));   // silu
      ACT[(size_t)(row0 + rloc) * II + ncol] = f2bf(s * u * w);
    }
  }
}

// ---------------- GEMM2: D[row][h] = ACT @ Wd ----------------
// Tile 128(M) x 128(N), BK=64. Wave w owns 128 M x 32 n (two 16-col frags).
__global__ __launch_bounds__(256) void gemm2_kernel(
    const u16* __restrict__ ACT, const float* __restrict__ wd,
    const int* __restrict__ tile_e, const int* __restrict__ tile_r,
    const int* __restrict__ ntiles, u16* __restrict__ D) {
  const int tileid = blockIdx.y;
  if (tileid >= *ntiles) return;
  const int e = tile_e[tileid];
  const int row0 = tile_r[tileid];
  const int n0 = blockIdx.x * 128;

  __shared__ __align__(16) u16 As[128 * 64];   // 16 KB

  const int tid = threadIdx.x;
  const int lane = tid & 63;
  const int wid = tid >> 6;
  const int fr = lane & 15, fq = lane >> 4;

  const int lrow = lane >> 3;
  const int sc8 = ((lane & 7) ^ lrow) * 8;

  const u16* gA[4]; u16* lA[4];
#pragma unroll
  for (int j = 0; j < 4; j++) {
    const int trow = j * 32 + wid * 8 + lrow;
    gA[j] = ACT + (size_t)(row0 + trow) * II + sc8;
    lA[j] = As + (j * 4 + wid) * 512;
  }

  const int nc0 = n0 + wid * 32 + fr;          // nf adds +16
  const float* dbase = wd + (size_t)e * II * HH + nc0;

  f32x4 acc[8][2];
  const f32x4 vz = {0.f, 0.f, 0.f, 0.f};
#pragma unroll
  for (int m = 0; m < 8; m++) { acc[m][0] = vz; acc[m][1] = vz; }

  for (int k0 = 0; k0 < II; k0 += 64) {
    float fb[2][2][8];   // [nf][ks][j]
#pragma unroll
    for (int nf = 0; nf < 2; nf++)
#pragma unroll
      for (int ks = 0; ks < 2; ks++)
#pragma unroll
        for (int j = 0; j < 8; j++)
          fb[nf][ks][j] = dbase[(size_t)(k0 + ks * 32 + fq * 8 + j) * HH + nf * 16];
    __syncthreads();
#pragma unroll
    for (int j = 0; j < 4; j++) gld16(gA[j] + k0, lA[j]);
    __syncthreads();

    short8 b[2][2];
#pragma unroll
    for (int nf = 0; nf < 2; nf++)
#pragma unroll
      for (int ks = 0; ks < 2; ks++)
#pragma unroll
        for (int j = 0; j < 8; j++)
          b[nf][ks][j] = f2bf_hw(fb[nf][ks][j]);

#pragma unroll
    for (int ks = 0; ks < 2; ks++)
#pragma unroll
      for (int m = 0; m < 8; m++) {
        const int r = m * 16 + fr;
        const short8 a = *(const short8*)(&As[r * 64 + (((ks * 4 + fq) ^ (r & 7)) * 8)]);
        acc[m][0] = __builtin_amdgcn_mfma_f32_16x16x32_bf16(a, b[0][ks], acc[m][0], 0, 0, 0);
        acc[m][1] = __builtin_amdgcn_mfma_f32_16x16x32_bf16(a, b[1][ks], acc[m][1], 0, 0, 0);
      }
  }

#pragma unroll
  for (int m = 0; m < 8; m++) {
#pragma unroll
    for (int jj = 0; jj < 4; jj++) {
      const int rloc = m * 16 + fq * 4 + jj;
      u16* dp = D + (size_t)(row0 + rloc) * HH + nc0;
      dp[0]  = f2bf(acc[m][0][jj]);
      dp[16] = f2bf(acc[m][1][jj]);
    }
  }
}

// ---------------- combine: out[t][h] = sum over t's valid pairs of D[row][h] ----------------
__global__ __launch_bounds__(256) void combine_kernel(
    const u16* __restrict__ D, const int* __restrict__ rowof,
    float* __restrict__ out) {
  const int t = blockIdx.x;
  const int h = threadIdx.x * 4;
  const int4 r4 = ((const int4*)rowof)[t];
  float a0 = 0.f, a1 = 0.f, a2 = 0.f, a3 = 0.f;
#define ACCUM(R)                                                     \
  if ((R) >= 0) {                                                    \
    u16x4 d = *(const u16x4*)(D + (size_t)(R) * HH + h);             \
    a0 += bf2f(d[0]); a1 += bf2f(d[1]); a2 += bf2f(d[2]); a3 += bf2f(d[3]); \
  }
  ACCUM(r4.x) ACCUM(r4.y) ACCUM(r4.z) ACCUM(r4.w)
#undef ACCUM
  float4 o = { a0, a1, a2, a3 };
  *(float4*)(out + (size_t)t * HH + h) = o;
}

// ---------------- launch ----------------
extern "C" void kernel_launch(void* const* d_in, const int* in_sizes, int n_in,
                              void* d_out, int out_size, void* d_ws, size_t ws_size,
                              hipStream_t stream) {
  const float* x = (const float*)d_in[0];
  const int* tidx = (const int*)d_in[1];
  const float* tw = (const float*)d_in[2];
  const float* wg = (const float*)d_in[3];
  const float* wu = (const float*)d_in[4];
  const float* wd = (const float*)d_in[5];
  float* out = (float*)d_out;

  // ws layout (bytes); no transposed weights anymore.
  char* ws = (char*)d_ws;
  int* ntiles = (int*)(ws + 0);
  int* tile_e = (int*)(ws + 1024);
  int* tile_r = (int*)(ws + 2048);
  int* perm = (int*)(ws + 4096);                 // 12288 ints
  float* wt = (float*)(ws + 53248);              // 12288 floats
  int* rowof = (int*)(ws + 102400);              // 8192 ints
  u16* xb = (u16*)(ws + 262144);                 // [2048][1024] bf16, 4 MB
  u16* D = (u16*)(ws + 4456448);                 // [MAXROWS][H] bf16, 25.2 MB
  u16* ACT = (u16*)(ws + 54788096);              // [MAXROWS][I] bf16, 12.58 MB

  prep_small<<<129, 1024, 0, stream>>>(x, tidx, tw, xb, perm, wt, rowof,
                                       tile_e, tile_r, ntiles);
  gemm1_kernel<<<dim3(II / 64, 80), 256, 0, stream>>>(xb, wg, wu, perm, wt,
                                                      tile_e, tile_r, ntiles, ACT);
  gemm2_kernel<<<dim3(HH / 128, 80), 256, 0, stream>>>(ACT, wd,
                                                       tile_e, tile_r, ntiles, D);
  combine_kernel<<<TT, 256, 0, stream>>>(D, rowof, out);
}

// Round 8
// 85.927 us; speedup vs baseline: 4.1834x; 1.0429x over previous
//
#include <hip/hip_runtime.h>
#include <hip/hip_bf16.h>
#include <stdint.h>

// Problem constants: B=1, S=2048, H=1024, I=512, E=16, K=4
#define HH 1024
#define II 512
#define EE 16
#define TT 2048
#define KTOP 4
#define PP (TT * KTOP)      // 8192 routed pairs
#define MAXROWS 12288       // padded row capacity

typedef unsigned short u16;
typedef unsigned int u32;
typedef __attribute__((ext_vector_type(8))) short short8;       // bf16 MFMA A/B frag
typedef __attribute__((ext_vector_type(4))) float f32x4;        // MFMA C/D frag
typedef __attribute__((ext_vector_type(4))) unsigned short u16x4;
typedef __attribute__((ext_vector_type(8))) unsigned short u16x8;

__device__ __forceinline__ u16 f2bf(float f) {  // fp32 -> bf16 RNE (manual)
  union { float f; unsigned u; } v; v.f = f;
  unsigned r = v.u + 0x7fffu + ((v.u >> 16) & 1u);
  return (u16)(r >> 16);
}
__device__ __forceinline__ float bf2f(u16 b) {
  union { unsigned u; float f; } v; v.u = ((unsigned)b) << 16; return v.f;
}
__device__ __forceinline__ short f2bf_hw(float f) {  // RNE via HW cvt
  __hip_bfloat16 h = __float2bfloat16(f);
  union { __hip_bfloat16 h; short s; } v; v.h = h; return v.s;
}

// Direct global->LDS DMA, 16B per lane; dest wave-uniform base + lane*16.
__device__ __forceinline__ void gld16(const u16* g, u16* l) {
  __builtin_amdgcn_global_load_lds(
      (const __attribute__((address_space(1))) unsigned int*)g,
      (__attribute__((address_space(3))) unsigned int*)l, 16, 0, 0);
}

// ================= prep: route (block 0, 16 waves) + x cvt (blocks 1..128) ==========
__global__ __launch_bounds__(1024) void prep_small(
    const float* __restrict__ x, const int* __restrict__ tidx,
    const float* __restrict__ tw,
    u16* __restrict__ xb,
    int* __restrict__ perm, float* __restrict__ wt, int* __restrict__ rowof,
    int* __restrict__ tile_e, int* __restrict__ tile_r,
    int* __restrict__ ntiles) {
  __shared__ int s_e[PP];          // bits0-3: e, bit4: valid, bits16+: rank
  __shared__ int whist[16][16];
  __shared__ int wbase[16][16];
  __shared__ int pad_lo[EE], pad_hi[EE];

  const int bid = blockIdx.x;
  const int tid = threadIdx.x;

  if (bid == 0) {
    const int lane = tid & 63;
    const int wv = tid >> 6;

#pragma unroll
    for (int i = 0; i < 2; i++) {
      const int t = tid + i * 1024;
      const int4 v = ((const int4*)tidx)[t];
      const bool v0 = (v.x != v.y) && (v.x != v.z) && (v.x != v.w);
      const bool v1 = (v.y != v.z) && (v.y != v.w);
      const bool v2 = (v.z != v.w);
      s_e[t * 4 + 0] = v.x | (v0 ? 16 : 0);
      s_e[t * 4 + 1] = v.y | (v1 ? 16 : 0);
      s_e[t * 4 + 2] = v.z | (v2 ? 16 : 0);
      s_e[t * 4 + 3] = v.w | 16;
    }
    __syncthreads();

    int h0, h1, h2, h3, h4, h5, h6, h7, h8, h9, h10, h11, h12, h13, h14, h15;
    h0=h1=h2=h3=h4=h5=h6=h7=h8=h9=h10=h11=h12=h13=h14=h15=0;
    const unsigned long long ltm = (1ull << lane) - 1ull;
    for (int c = 0; c < 8; c++) {
      const int p = (wv << 9) + (c << 6) + lane;
      const int se = s_e[p];
      const int e = se & 15;
      const bool valid = (se & 16) != 0;
      int rank = 0;
#define RANK_STEP(J, HJ)                                            \
      {                                                             \
        unsigned long long m = __ballot(valid && (e == J));         \
        if (valid && (e == J)) rank = HJ + __popcll(m & ltm);       \
        HJ += __popcll(m);                                          \
      }
      RANK_STEP(0, h0)  RANK_STEP(1, h1)  RANK_STEP(2, h2)  RANK_STEP(3, h3)
      RANK_STEP(4, h4)  RANK_STEP(5, h5)  RANK_STEP(6, h6)  RANK_STEP(7, h7)
      RANK_STEP(8, h8)  RANK_STEP(9, h9)  RANK_STEP(10, h10) RANK_STEP(11, h11)
      RANK_STEP(12, h12) RANK_STEP(13, h13) RANK_STEP(14, h14) RANK_STEP(15, h15)
#undef RANK_STEP
      if (valid) s_e[p] = se | (rank << 16);
    }
    if (lane == 0) {
      whist[wv][0] = h0;   whist[wv][1] = h1;   whist[wv][2] = h2;   whist[wv][3] = h3;
      whist[wv][4] = h4;   whist[wv][5] = h5;   whist[wv][6] = h6;   whist[wv][7] = h7;
      whist[wv][8] = h8;   whist[wv][9] = h9;   whist[wv][10] = h10; whist[wv][11] = h11;
      whist[wv][12] = h12; whist[wv][13] = h13; whist[wv][14] = h14; whist[wv][15] = h15;
    }
    __syncthreads();

    if (tid == 0) {
      int off = 0, nt = 0;
      for (int j = 0; j < EE; j++) {
        int tot = 0;
        for (int w = 0; w < 16; w++) { wbase[w][j] = off + tot; tot += whist[w][j]; }
        const int cap = (tot + 127) & ~127;
        pad_lo[j] = off + tot;
        pad_hi[j] = off + cap;
        for (int m0 = 0; m0 < cap; m0 += 128) { tile_e[nt] = j; tile_r[nt] = off + m0; nt++; }
        off += cap;
      }
      *ntiles = nt;
    }
    __syncthreads();

#pragma unroll
    for (int i = 0; i < 8; i++) {
      const int p = i * 1024 + tid;
      const int se = s_e[p];
      int pos = -1;
      if (se & 16) {
        const int e = se & 15;
        const int r = se >> 16;
        pos = wbase[p >> 9][e] + r;
        perm[pos] = p >> 2;
        wt[pos] = tw[p];
      }
      rowof[p] = pos;
    }
    for (int j = 0; j < EE; j++) {
      const int lo = pad_lo[j], hi = pad_hi[j];
      for (int i = lo + tid; i < hi; i += 1024) {
        perm[i] = 0;          // pad: token 0 with weight 0 contributes nothing
        wt[i] = 0.f;
      }
    }
    return;
  }

  // ---- x fp32 -> bf16, 16 elems/thread ----
  const int base = ((bid - 1) * 1024 + tid) * 16;
  f32x4 v0 = *(const f32x4*)(x + base);
  f32x4 v1 = *(const f32x4*)(x + base + 4);
  f32x4 v2 = *(const f32x4*)(x + base + 8);
  f32x4 v3 = *(const f32x4*)(x + base + 12);
  u16x8 o0 = { f2bf(v0[0]), f2bf(v0[1]), f2bf(v0[2]), f2bf(v0[3]),
               f2bf(v1[0]), f2bf(v1[1]), f2bf(v1[2]), f2bf(v1[3]) };
  u16x8 o1 = { f2bf(v2[0]), f2bf(v2[1]), f2bf(v2[2]), f2bf(v2[3]),
               f2bf(v3[0]), f2bf(v3[1]), f2bf(v3[2]), f2bf(v3[3]) };
  *(u16x8*)(xb + base) = o0;
  *(u16x8*)(xb + base + 8) = o1;
}

// ---------------- GEMM1: ACT = silu(x@Wg) * (x@Wu) * gate_weight ----------------
// Tile 128(M) x 64(N), BK=64, software-pipelined 1-deep:
// prefetch B[t+1] (regs) + A[t+1] (LDS dbuf) before computing tile t, so the
// vmcnt drain at the barrier lands after 32 MFMAs instead of right after issue.
#define G1_LOADB(FG, FU, K0)                                           \
  _Pragma("unroll")                                                    \
  for (int ks = 0; ks < 2; ks++)                                       \
    _Pragma("unroll")                                                  \
    for (int j = 0; j < 8; j++) {                                      \
      const size_t koff = (size_t)((K0) + ks * 32 + fq * 8 + j) * II;  \
      FG[ks][j] = gbase[koff];                                         \
      FU[ks][j] = ubase[koff];                                         \
    }

#define G1_STAGE(BUF, K0)                                              \
  _Pragma("unroll")                                                    \
  for (int j = 0; j < 4; j++) gld16(gA[j] + (K0), (BUF) + (j * 4 + wid) * 512);

#define G1_COMPUTE(FG, FU, ASBUF)                                      \
  {                                                                    \
    short8 bg[2], bu[2];                                               \
    _Pragma("unroll")                                                  \
    for (int ks = 0; ks < 2; ks++)                                     \
      _Pragma("unroll")                                                \
      for (int j = 0; j < 8; j++) {                                    \
        bg[ks][j] = f2bf_hw(FG[ks][j]);                                \
        bu[ks][j] = f2bf_hw(FU[ks][j]);                                \
      }                                                                \
    _Pragma("unroll")                                                  \
    for (int ks = 0; ks < 2; ks++)                                     \
      _Pragma("unroll")                                                \
      for (int m = 0; m < 8; m++) {                                    \
        const int r = m * 16 + fr;                                     \
        const short8 a = *(const short8*)(&(ASBUF)[r * 64 + (((ks * 4 + fq) ^ (r & 7)) * 8)]); \
        accg[m] = __builtin_amdgcn_mfma_f32_16x16x32_bf16(a, bg[ks], accg[m], 0, 0, 0); \
        accu[m] = __builtin_amdgcn_mfma_f32_16x16x32_bf16(a, bu[ks], accu[m], 0, 0, 0); \
      }                                                                \
  }

__global__ __launch_bounds__(256) void gemm1_kernel(
    const u16* __restrict__ xb, const float* __restrict__ wg,
    const float* __restrict__ wu,
    const int* __restrict__ perm, const float* __restrict__ wt,
    const int* __restrict__ tile_e, const int* __restrict__ tile_r,
    const int* __restrict__ ntiles, u16* __restrict__ ACT) {
  const int tileid = blockIdx.y;
  if (tileid >= *ntiles) return;
  const int e = tile_e[tileid];
  const int row0 = tile_r[tileid];
  const int n0 = blockIdx.x * 64;

  __shared__ __align__(16) u16 As[2][128 * 64];   // 32 KB double buffer

  const int tid = threadIdx.x;
  const int lane = tid & 63;
  const int wid = tid >> 6;
  const int fr = lane & 15, fq = lane >> 4;

  const int lrow = lane >> 3;
  const int sc8 = ((lane & 7) ^ lrow) * 8;     // pre-swizzled source chunk

  const u16* gA[4];
#pragma unroll
  for (int j = 0; j < 4; j++) {
    const int trow = j * 32 + wid * 8 + lrow;
    gA[j] = xb + (size_t)perm[row0 + trow] * HH + sc8;
  }
  u16* const As0 = &As[0][0];
  u16* const As1 = &As[1][0];

  const int ncol = n0 + wid * 16 + fr;         // this lane's output column
  const float* gbase = wg + (size_t)e * HH * II + ncol;
  const float* ubase = wu + (size_t)e * HH * II + ncol;

  f32x4 accg[8], accu[8];
  const f32x4 vz = {0.f, 0.f, 0.f, 0.f};
#pragma unroll
  for (int m = 0; m < 8; m++) { accg[m] = vz; accu[m] = vz; }

  float fgA[2][8], fuA[2][8], fgB[2][8], fuB[2][8];

  // prologue: tile 0 into set A / As0
  G1_LOADB(fgA, fuA, 0)
  G1_STAGE(As0, 0)
  __syncthreads();

  for (int t = 0; t < 16; t += 2) {
    // phase 0: prefetch tile t+1, compute tile t
    G1_LOADB(fgB, fuB, (t + 1) * 64)
    G1_STAGE(As1, (t + 1) * 64)
    G1_COMPUTE(fgA, fuA, As0)
    __syncthreads();
    // phase 1: prefetch tile t+2, compute tile t+1
    if (t < 14) {
      G1_LOADB(fgA, fuA, (t + 2) * 64)
      G1_STAGE(As0, (t + 2) * 64)
    }
    G1_COMPUTE(fgB, fuB, As1)
    __syncthreads();
  }

  // C/D: col = lane&15 (=fr), row = fq*4 + jj within each 16-row m-frag
#pragma unroll
  for (int m = 0; m < 8; m++) {
#pragma unroll
    for (int jj = 0; jj < 4; jj++) {
      const int rloc = m * 16 + fq * 4 + jj;
      const float w = wt[row0 + rloc];
      const float g = accg[m][jj];
      const float u = accu[m][jj];
      const float s = g / (1.f + __expf(-g));   // silu
      ACT[(size_t)(row0 + rloc) * II + ncol] = f2bf(s * u * w);
    }
  }
}

// ---------------- GEMM2: D[row][h] = ACT @ Wd (pipelined like gemm1) ----------------
#define G2_LOADB(FB, K0)                                               \
  _Pragma("unroll")                                                    \
  for (int nf = 0; nf < 2; nf++)                                       \
    _Pragma("unroll")                                                  \
    for (int ks = 0; ks < 2; ks++)                                     \
      _Pragma("unroll")                                                \
      for (int j = 0; j < 8; j++)                                      \
        FB[nf][ks][j] = dbase[(size_t)((K0) + ks * 32 + fq * 8 + j) * HH + nf * 16];

#define G2_STAGE(BUF, K0)                                              \
  _Pragma("unroll")                                                    \
  for (int j = 0; j < 4; j++) gld16(gA[j] + (K0), (BUF) + (j * 4 + wid) * 512);

#define G2_COMPUTE(FB, ASBUF)                                          \
  {                                                                    \
    short8 b[2][2];                                                    \
    _Pragma("unroll")                                                  \
    for (int nf = 0; nf < 2; nf++)                                     \
      _Pragma("unroll")                                                \
      for (int ks = 0; ks < 2; ks++)                                   \
        _Pragma("unroll")                                              \
        for (int j = 0; j < 8; j++)                                    \
          b[nf][ks][j] = f2bf_hw(FB[nf][ks][j]);                       \
    _Pragma("unroll")                                                  \
    for (int ks = 0; ks < 2; ks++)                                     \
      _Pragma("unroll")                                                \
      for (int m = 0; m < 8; m++) {                                    \
        const int r = m * 16 + fr;                                     \
        const short8 a = *(const short8*)(&(ASBUF)[r * 64 + (((ks * 4 + fq) ^ (r & 7)) * 8)]); \
        acc[m][0] = __builtin_amdgcn_mfma_f32_16x16x32_bf16(a, b[0][ks], acc[m][0], 0, 0, 0); \
        acc[m][1] = __builtin_amdgcn_mfma_f32_16x16x32_bf16(a, b[1][ks], acc[m][1], 0, 0, 0); \
      }                                                                \
  }

__global__ __launch_bounds__(256) void gemm2_kernel(
    const u16* __restrict__ ACT, const float* __restrict__ wd,
    const int* __restrict__ tile_e, const int* __restrict__ tile_r,
    const int* __restrict__ ntiles, u16* __restrict__ D) {
  const int tileid = blockIdx.y;
  if (tileid >= *ntiles) return;
  const int e = tile_e[tileid];
  const int row0 = tile_r[tileid];
  const int n0 = blockIdx.x * 128;

  __shared__ __align__(16) u16 As[2][128 * 64];   // 32 KB double buffer

  const int tid = threadIdx.x;
  const int lane = tid & 63;
  const int wid = tid >> 6;
  const int fr = lane & 15, fq = lane >> 4;

  const int lrow = lane >> 3;
  const int sc8 = ((lane & 7) ^ lrow) * 8;

  const u16* gA[4];
#pragma unroll
  for (int j = 0; j < 4; j++) {
    const int trow = j * 32 + wid * 8 + lrow;
    gA[j] = ACT + (size_t)(row0 + trow) * II + sc8;
  }
  u16* const As0 = &As[0][0];
  u16* const As1 = &As[1][0];

  const int nc0 = n0 + wid * 32 + fr;          // nf adds +16
  const float* dbase = wd + (size_t)e * II * HH + nc0;

  f32x4 acc[8][2];
  const f32x4 vz = {0.f, 0.f, 0.f, 0.f};
#pragma unroll
  for (int m = 0; m < 8; m++) { acc[m][0] = vz; acc[m][1] = vz; }

  float fbA[2][2][8], fbB[2][2][8];

  G2_LOADB(fbA, 0)
  G2_STAGE(As0, 0)
  __syncthreads();

  for (int t = 0; t < 8; t += 2) {
    G2_LOADB(fbB, (t + 1) * 64)
    G2_STAGE(As1, (t + 1) * 64)
    G2_COMPUTE(fbA, As0)
    __syncthreads();
    if (t < 6) {
      G2_LOADB(fbA, (t + 2) * 64)
      G2_STAGE(As0, (t + 2) * 64)
    }
    G2_COMPUTE(fbB, As1)
    __syncthreads();
  }

#pragma unroll
  for (int m = 0; m < 8; m++) {
#pragma unroll
    for (int jj = 0; jj < 4; jj++) {
      const int rloc = m * 16 + fq * 4 + jj;
      u16* dp = D + (size_t)(row0 + rloc) * HH + nc0;
      dp[0]  = f2bf(acc[m][0][jj]);
      dp[16] = f2bf(acc[m][1][jj]);
    }
  }
}

// ---------------- combine: out[t][h] = sum over t's valid pairs of D[row][h] ----------------
__global__ __launch_bounds__(256) void combine_kernel(
    const u16* __restrict__ D, const int* __restrict__ rowof,
    float* __restrict__ out) {
  const int t = blockIdx.x;
  const int h = threadIdx.x * 4;
  const int4 r4 = ((const int4*)rowof)[t];
  float a0 = 0.f, a1 = 0.f, a2 = 0.f, a3 = 0.f;
#define ACCUM(R)                                                     \
  if ((R) >= 0) {                                                    \
    u16x4 d = *(const u16x4*)(D + (size_t)(R) * HH + h);             \
    a0 += bf2f(d[0]); a1 += bf2f(d[1]); a2 += bf2f(d[2]); a3 += bf2f(d[3]); \
  }
  ACCUM(r4.x) ACCUM(r4.y) ACCUM(r4.z) ACCUM(r4.w)
#undef ACCUM
  float4 o = { a0, a1, a2, a3 };
  *(float4*)(out + (size_t)t * HH + h) = o;
}

// ---------------- launch ----------------
extern "C" void kernel_launch(void* const* d_in, const int* in_sizes, int n_in,
                              void* d_out, int out_size, void* d_ws, size_t ws_size,
                              hipStream_t stream) {
  const float* x = (const float*)d_in[0];
  const int* tidx = (const int*)d_in[1];
  const float* tw = (const float*)d_in[2];
  const float* wg = (const float*)d_in[3];
  const float* wu = (const float*)d_in[4];
  const float* wd = (const float*)d_in[5];
  float* out = (float*)d_out;

  char* ws = (char*)d_ws;
  int* ntiles = (int*)(ws + 0);
  int* tile_e = (int*)(ws + 1024);
  int* tile_r = (int*)(ws + 2048);
  int* perm = (int*)(ws + 4096);                 // 12288 ints
  float* wt = (float*)(ws + 53248);              // 12288 floats
  int* rowof = (int*)(ws + 102400);              // 8192 ints
  u16* xb = (u16*)(ws + 262144);                 // [2048][1024] bf16, 4 MB
  u16* D = (u16*)(ws + 4456448);                 // [MAXROWS][H] bf16, 25.2 MB
  u16* ACT = (u16*)(ws + 54788096);              // [MAXROWS][I] bf16, 12.58 MB

  prep_small<<<129, 1024, 0, stream>>>(x, tidx, tw, xb, perm, wt, rowof,
                                       tile_e, tile_r, ntiles);
  gemm1_kernel<<<dim3(II / 64, 80), 256, 0, stream>>>(xb, wg, wu, perm, wt,
                                                      tile_e, tile_r, ntiles, ACT);
  gemm2_kernel<<<dim3(HH / 128, 80), 256, 0, stream>>>(ACT, wd,
                                                       tile_e, tile_r, ntiles, D);
  combine_kernel<<<TT, 256, 0, stream>>>(D, rowof, out);
}